// Round 6
// baseline (590.428 us; speedup 1.0000x reference)
//
#include <hip/hip_runtime.h>

// ---------------------------------------------------------------------------
// RoBERTa self-attention: QKV projection (bf16 MFMA) + flash attention.
// B=4, S=2048, D=1024, H=16, HD=64.  fp32 in/out, bf16 internal, fp32 acc.
// R5: mask row staged to LDS once (pre-scaled by log2e) -- R4's per-tile
//     global mask loads forced vmcnt(0) drains of the K/V prefetch every
//     tile (vmcnt is in-order). + s_setprio around MFMA clusters (T5),
//     __launch_bounds__(256,4).
// ---------------------------------------------------------------------------

typedef __bf16 bf16;
typedef bf16  bf16x8 __attribute__((ext_vector_type(8)));
typedef bf16  bf16x4 __attribute__((ext_vector_type(4)));
typedef float f32x4  __attribute__((ext_vector_type(4)));
typedef float f32x16 __attribute__((ext_vector_type(16)));

#define MFMA16(A, B, C) __builtin_amdgcn_mfma_f32_16x16x32_bf16((A), (B), (C), 0, 0, 0)
#define MFMA32(A, B, C) __builtin_amdgcn_mfma_f32_32x32x16_bf16((A), (B), (C), 0, 0, 0)

constexpr int BB = 4, SS = 2048, DD = 1024, HH = 16, HD = 64;
constexpr float SCALE = 0.125f;                       // 1/sqrt(64)
constexpr float LOG2E = 1.44269504088896f;
constexpr float SCALE_LOG2E = SCALE * LOG2E;

__device__ __forceinline__ float fast_exp2(float x) {
#if __has_builtin(__builtin_amdgcn_exp2f)
  return __builtin_amdgcn_exp2f(x);
#else
  return exp2f(x);
#endif
}

__device__ __forceinline__ bf16x8 cvt8(f32x4 a, f32x4 b) {
  bf16x8 r;
  r[0] = (bf16)a[0]; r[1] = (bf16)a[1]; r[2] = (bf16)a[2]; r[3] = (bf16)a[3];
  r[4] = (bf16)b[0]; r[5] = (bf16)b[1]; r[6] = (bf16)b[2]; r[7] = (bf16)b[3];
  return r;
}

__device__ __forceinline__ unsigned pack2(float lo, float hi) {
  union { bf16 h[2]; unsigned u; } r;
  r.h[0] = (bf16)lo; r.h[1] = (bf16)hi;
  return r.u;
}

// ---------------------------------------------------------------------------
// Kernel 1: Y = X @ W^T + b, output bf16.  (unchanged: ~63us, ~817 TF)
//   z==0 -> Q [8192,1024];  z==1 -> K [8192,1024];
//   z==2 -> V transposed per-head: Vt[(b*16+h)*64 + d][s]
// ---------------------------------------------------------------------------
__global__ __launch_bounds__(256, 2) void qkv_gemm(
    const float* __restrict__ X,
    const float* __restrict__ Wq, const float* __restrict__ bq,
    const float* __restrict__ Wk, const float* __restrict__ bk,
    const float* __restrict__ Wv, const float* __restrict__ bv,
    bf16* __restrict__ Qo, bf16* __restrict__ Ko, bf16* __restrict__ Vt) {
  const int z = blockIdx.z;
  const float* W    = (z == 0) ? Wq : (z == 1) ? Wk : Wv;
  const float* bias = (z == 0) ? bq : (z == 1) ? bk : bv;

  __shared__ bf16 As[128 * 64];
  __shared__ bf16 Bs[128 * 64];

  const int tid  = threadIdx.x;
  const int lane = tid & 63;
  const int w    = tid >> 6;
  const int wr   = w >> 1, wc = w & 1;
  const int m0   = blockIdx.x * 128;
  const int n0   = blockIdx.y * 128;
  const int c    = lane & 15, g = lane >> 4;

  f32x4 acc[4][4];
#pragma unroll
  for (int i = 0; i < 4; ++i)
#pragma unroll
    for (int j = 0; j < 4; ++j) acc[i][j] = f32x4{0.f, 0.f, 0.f, 0.f};

  for (int k0 = 0; k0 < DD; k0 += 64) {
    __syncthreads();
#pragma unroll
    for (int it = 0; it < 4; ++it) {
      int idx = tid + it * 256;       // chunk id (chunk = 8 bf16)
      int row = idx >> 3, c8 = idx & 7;
      const f32x4* ga = (const f32x4*)(X + (size_t)(m0 + row) * DD + k0 + c8 * 8);
      f32x4 a0 = ga[0], a1 = ga[1];
      *(bf16x8*)(&As[row * 64 + ((c8 * 8) ^ ((row & 7) << 3))]) = cvt8(a0, a1);
      const f32x4* gb = (const f32x4*)(W + (size_t)(n0 + row) * DD + k0 + c8 * 8);
      f32x4 b0 = gb[0], b1 = gb[1];
      *(bf16x8*)(&Bs[row * 64 + ((c8 * 8) ^ ((row & 7) << 3))]) = cvt8(b0, b1);
    }
    __syncthreads();

#pragma unroll
    for (int kk = 0; kk < 64; kk += 32) {
      bf16x8 af[4], bfr[4];
#pragma unroll
      for (int m = 0; m < 4; ++m) {
        int row = wr * 64 + m * 16 + c;
        af[m] = *(const bf16x8*)(&As[row * 64 + ((kk + g * 8) ^ ((row & 7) << 3))]);
      }
#pragma unroll
      for (int n = 0; n < 4; ++n) {
        int row = wc * 64 + n * 16 + c;
        bfr[n] = *(const bf16x8*)(&Bs[row * 64 + ((kk + g * 8) ^ ((row & 7) << 3))]);
      }
#pragma unroll
      for (int m = 0; m < 4; ++m)
#pragma unroll
        for (int n = 0; n < 4; ++n)
          acc[m][n] = MFMA16(af[m], bfr[n], acc[m][n]);
    }
  }

#pragma unroll
  for (int n = 0; n < 4; ++n) {
    int colg = n0 + wc * 64 + n * 16 + c;
    float bv_ = bias[colg];
#pragma unroll
    for (int m = 0; m < 4; ++m) {
      int rowg = m0 + wr * 64 + m * 16 + g * 4;
      f32x4 a = acc[m][n];
      if (z < 2) {
        bf16* dst = (z == 0) ? Qo : Ko;
#pragma unroll
        for (int j = 0; j < 4; ++j)
          dst[(size_t)(rowg + j) * DD + colg] = (bf16)(a[j] + bv_);
      } else {
        int bi = rowg >> 11, s = rowg & 2047;
        int hh = colg >> 6, dd = colg & 63;
        bf16x4 pv;
#pragma unroll
        for (int j = 0; j < 4; ++j) pv[j] = (bf16)(a[j] + bv_);
        *(bf16x4*)(&Vt[(((size_t)bi * HH + hh) * HD + dd) * SS + s]) = pv;
      }
    }
  }
}

// ---------------------------------------------------------------------------
// Kernel 2: flash attention, 32x32x16 MFMA. Grid (B*H, S/128), 4 waves.
// Wave w owns q rows [qb*128 + w*32, +32).  Per-lane: q = lane&31, hi=lane>>5.
// Mask row (pre-scaled by log2e) lives in LDS: per-tile mask reads are
// broadcast ds_reads (lgkm), so the only vmcnt wait per tile is the ds_write
// of the prefetched K/V tile -> stage loads overlap the whole tile compute.
// ---------------------------------------------------------------------------
__global__ __launch_bounds__(256, 4) void attn(
    const bf16* __restrict__ Q,   // [B*S, D]
    const bf16* __restrict__ K,   // [B*S, D]
    const bf16* __restrict__ Vt,  // [(b*16+h)*64 + d][S]
    const float* __restrict__ mask,  // [B, S] additive
    float* __restrict__ out) {       // [B, S, D] fp32
  __shared__ bf16 Ks[2][64 * 64];
  __shared__ bf16 Vs[2][64 * 64];
  __shared__ float Ms[SS];   // mask * log2e

  const int bh = blockIdx.x;  // 0..63
  const int qb = blockIdx.y;  // 0..15
  const int b = bh >> 4, h = bh & 15;
  const int tid = threadIdx.x;
  const int lane = tid & 63;
  const int w = tid >> 6;
  const int l31 = lane & 31, hi = lane >> 5;
  const int hi4 = hi * 4, hi8 = hi * 8;
  const int qg = qb * 128 + w * 32 + l31;  // this lane's q row

  const bf16* qptr = Q + ((size_t)(b * SS + qg)) * DD + h * HD;
  bf16x8 qB[4];
#pragma unroll
  for (int ks = 0; ks < 4; ++ks)
    qB[ks] = *(const bf16x8*)(qptr + ks * 16 + hi8);

  const bf16* Kbase = K + ((size_t)b * SS) * DD + h * HD;
  const bf16* Vbase = Vt + ((size_t)bh * HD) * SS;

  const int srow = lane >> 3;
  const int sj   = lane & 7;
  const int r0   = w * 16 + srow, r1 = r0 + 8;
  const int swz0 = r0 * 64 + ((sj ^ (r0 & 7)) * 8);
  const int swz1 = r1 * 64 + ((sj ^ (r1 & 7)) * 8);

  f32x4 lacc = {0.f, 0.f, 0.f, 0.f};
  f32x16 acc[2] = {};

  bf16x8 stK0, stK1, stV0, stV1;

  // ---- prologue: mask row -> LDS (pre-scaled), stage tile 0 into buf 0 ----
  {
    const float* mbase = mask + b * SS;
    f32x4 m0 = *(const f32x4*)(mbase + tid * 8);
    f32x4 m1 = *(const f32x4*)(mbase + tid * 8 + 4);
    *(f32x4*)(&Ms[tid * 8])     = m0 * LOG2E;
    *(f32x4*)(&Ms[tid * 8 + 4]) = m1 * LOG2E;
  }
  stK0 = *(const bf16x8*)(Kbase + (size_t)r0 * DD + sj * 8);
  stK1 = *(const bf16x8*)(Kbase + (size_t)r1 * DD + sj * 8);
  stV0 = *(const bf16x8*)(Vbase + (size_t)r0 * SS + sj * 8);
  stV1 = *(const bf16x8*)(Vbase + (size_t)r1 * SS + sj * 8);
  *(bf16x8*)(&Ks[0][swz0]) = stK0;
  *(bf16x8*)(&Ks[0][swz1]) = stK1;
  *(bf16x8*)(&Vs[0][swz0]) = stV0;
  *(bf16x8*)(&Vs[0][swz1]) = stV1;
  __syncthreads();

  for (int t2 = 0; t2 < 16; ++t2) {
#pragma unroll
    for (int half = 0; half < 2; ++half) {
      const int t = t2 * 2 + half;
      const int kv0 = t * 64;
      const bool last = (t == 31);

      // ---- issue next tile's global loads (hide under compute) ----
      if (!last) {
        const int sg = kv0 + 64;
        stK0 = *(const bf16x8*)(Kbase + (size_t)(sg + r0) * DD + sj * 8);
        stK1 = *(const bf16x8*)(Kbase + (size_t)(sg + r1) * DD + sj * 8);
        stV0 = *(const bf16x8*)(Vbase + (size_t)r0 * SS + sg + sj * 8);
        stV1 = *(const bf16x8*)(Vbase + (size_t)r1 * SS + sg + sj * 8);
      }

      // ---- QK^T: st[kvb] over 4 d-slices ----
      f32x16 st[2] = {};
      __builtin_amdgcn_s_setprio(1);
#pragma unroll
      for (int kvb = 0; kvb < 2; ++kvb) {
        const int krow = kvb * 32 + l31;
        const int kro = krow * 64, kr7 = krow & 7;
#pragma unroll
        for (int ks = 0; ks < 4; ++ks) {
          bf16x8 ka = *(const bf16x8*)(&Ks[half][kro + (((2 * ks + hi) ^ kr7) * 8)]);
          st[kvb] = MFMA32(ka, qB[ks], st[kvb]);
        }
      }
      __builtin_amdgcn_s_setprio(0);

      // ---- V^T frags (issue early; latency hides under softmax) ----
      bf16x8 va[2][4];
#pragma unroll
      for (int db = 0; db < 2; ++db) {
        const int vrow = db * 32 + l31;
        const int vro = vrow * 64, vr7 = vrow & 7;
#pragma unroll
        for (int sl = 0; sl < 4; ++sl)
          va[db][sl] = *(const bf16x8*)(&Vs[half][vro + (((2 * sl + hi) ^ vr7) * 8)]);
      }

      // ---- softmax: p = exp2(st*scale*log2e + ms), mask from LDS ----
#pragma unroll
      for (int kvb = 0; kvb < 2; ++kvb) {
#pragma unroll
        for (int rg = 0; rg < 4; ++rg) {
          f32x4 mk = *(const f32x4*)(&Ms[kv0 + kvb * 32 + rg * 8 + hi4]);
#pragma unroll
          for (int j = 0; j < 4; ++j) {
            float e = fast_exp2(fmaf(st[kvb][rg * 4 + j], SCALE_LOG2E, mk[j]));
            st[kvb][rg * 4 + j] = e;
            lacc[j] += e;
          }
        }
      }

      // ---- P repack (shfl_xor(32) + select) and PV MFMAs ----
      __builtin_amdgcn_s_setprio(1);
#pragma unroll
      for (int kvb = 0; kvb < 2; ++kvb) {
#pragma unroll
        for (int s2 = 0; s2 < 2; ++s2) {
          unsigned L0 = pack2(st[kvb][8 * s2 + 0], st[kvb][8 * s2 + 1]);
          unsigned L1 = pack2(st[kvb][8 * s2 + 2], st[kvb][8 * s2 + 3]);
          unsigned H0 = pack2(st[kvb][8 * s2 + 4], st[kvb][8 * s2 + 5]);
          unsigned H1 = pack2(st[kvb][8 * s2 + 6], st[kvb][8 * s2 + 7]);
          unsigned xL0 = (unsigned)__shfl_xor((int)L0, 32);
          unsigned xL1 = (unsigned)__shfl_xor((int)L1, 32);
          unsigned xH0 = (unsigned)__shfl_xor((int)H0, 32);
          unsigned xH1 = (unsigned)__shfl_xor((int)H1, 32);
          union { unsigned u[4]; bf16x8 v; } pb;
          pb.u[0] = hi ? xH0 : L0;   // e0,e1: own L0 / partner H0
          pb.u[1] = hi ? xH1 : L1;   // e2,e3
          pb.u[2] = hi ? H0 : xL0;   // e4,e5: partner L0 / own H0
          pb.u[3] = hi ? H1 : xL1;   // e6,e7
          const int sl = kvb * 2 + s2;
          acc[0] = MFMA32(va[0][sl], pb.v, acc[0]);
          acc[1] = MFMA32(va[1][sl], pb.v, acc[1]);
        }
      }
      __builtin_amdgcn_s_setprio(0);

      // ---- write next tile to other buffer, then barrier ----
      if (!last) {
        *(bf16x8*)(&Ks[half ^ 1][swz0]) = stK0;
        *(bf16x8*)(&Ks[half ^ 1][swz1]) = stK1;
        *(bf16x8*)(&Vs[half ^ 1][swz0]) = stV0;
        *(bf16x8*)(&Vs[half ^ 1][swz1]) = stV1;
      }
      __syncthreads();
    }
  }

  // ---- lsum: halves hold disjoint kv subsets; combine across hi ----
  float ls = lacc[0] + lacc[1] + lacc[2] + lacc[3];
  ls += __shfl_xor(ls, 32);
  const float inv = 1.0f / ls;

  // ---- store ctx[qg][d] = acc^T * inv;  d = 32db + 8rg + 4hi + j ----
  float* op = out + ((size_t)(b * SS + qg)) * DD + h * HD;
#pragma unroll
  for (int db = 0; db < 2; ++db)
#pragma unroll
    for (int rg = 0; rg < 4; ++rg) {
      f32x4 v;
#pragma unroll
      for (int j = 0; j < 4; ++j) v[j] = acc[db][rg * 4 + j] * inv;
      *(f32x4*)(op + db * 32 + rg * 8 + hi4) = v;
    }
}

// ---------------------------------------------------------------------------
extern "C" void kernel_launch(void* const* d_in, const int* in_sizes, int n_in,
                              void* d_out, int out_size, void* d_ws, size_t ws_size,
                              hipStream_t stream) {
  const float* X    = (const float*)d_in[0];
  const float* mask = (const float*)d_in[1];
  const float* Wq   = (const float*)d_in[2];
  const float* bq   = (const float*)d_in[3];
  const float* Wk   = (const float*)d_in[4];
  const float* bk   = (const float*)d_in[5];
  const float* Wv   = (const float*)d_in[6];
  const float* bv   = (const float*)d_in[7];

  bf16* Qw = (bf16*)d_ws;
  bf16* Kw = Qw + (size_t)BB * SS * DD;
  bf16* Vt = Kw + (size_t)BB * SS * DD;

  dim3 g1((BB * SS) / 128, DD / 128, 3);
  qkv_gemm<<<g1, 256, 0, stream>>>(X, Wq, bq, Wk, bk, Wv, bv, Qw, Kw, Vt);

  dim3 g2(BB * HH, SS / 128);  // 64 x 16
  attn<<<g2, 256, 0, stream>>>(Qw, Kw, Vt, mask, (float*)d_out);
}

// Round 7
// 251.818 us; speedup vs baseline: 2.3447x; 2.3447x over previous
//
#include <hip/hip_runtime.h>

// ---------------------------------------------------------------------------
// RoBERTa self-attention: QKV projection (bf16 MFMA) + flash attention.
// B=4, S=2048, D=1024, H=16, HD=64.  fp32 in/out, bf16 internal, fp32 acc.
// R6: revert R5's __launch_bounds__(256,4) -- it capped VGPR at 64 and the
//     kernel spilled to scratch (FETCH 41MB->950MB). Keep mask-in-LDS
//     (removes per-tile vmcnt drain of K/V prefetch) + setprio(T5).
// ---------------------------------------------------------------------------

typedef __bf16 bf16;
typedef bf16  bf16x8 __attribute__((ext_vector_type(8)));
typedef bf16  bf16x4 __attribute__((ext_vector_type(4)));
typedef float f32x4  __attribute__((ext_vector_type(4)));
typedef float f32x16 __attribute__((ext_vector_type(16)));

#define MFMA16(A, B, C) __builtin_amdgcn_mfma_f32_16x16x32_bf16((A), (B), (C), 0, 0, 0)
#define MFMA32(A, B, C) __builtin_amdgcn_mfma_f32_32x32x16_bf16((A), (B), (C), 0, 0, 0)

constexpr int BB = 4, SS = 2048, DD = 1024, HH = 16, HD = 64;
constexpr float SCALE = 0.125f;                       // 1/sqrt(64)
constexpr float LOG2E = 1.44269504088896f;
constexpr float SCALE_LOG2E = SCALE * LOG2E;

__device__ __forceinline__ float fast_exp2(float x) {
#if __has_builtin(__builtin_amdgcn_exp2f)
  return __builtin_amdgcn_exp2f(x);
#else
  return exp2f(x);
#endif
}

__device__ __forceinline__ bf16x8 cvt8(f32x4 a, f32x4 b) {
  bf16x8 r;
  r[0] = (bf16)a[0]; r[1] = (bf16)a[1]; r[2] = (bf16)a[2]; r[3] = (bf16)a[3];
  r[4] = (bf16)b[0]; r[5] = (bf16)b[1]; r[6] = (bf16)b[2]; r[7] = (bf16)b[3];
  return r;
}

__device__ __forceinline__ unsigned pack2(float lo, float hi) {
  union { bf16 h[2]; unsigned u; } r;
  r.h[0] = (bf16)lo; r.h[1] = (bf16)hi;
  return r.u;
}

// ---------------------------------------------------------------------------
// Kernel 1: Y = X @ W^T + b, output bf16.  (unchanged: ~63us, ~817 TF)
//   z==0 -> Q [8192,1024];  z==1 -> K [8192,1024];
//   z==2 -> V transposed per-head: Vt[(b*16+h)*64 + d][s]
// ---------------------------------------------------------------------------
__global__ __launch_bounds__(256, 2) void qkv_gemm(
    const float* __restrict__ X,
    const float* __restrict__ Wq, const float* __restrict__ bq,
    const float* __restrict__ Wk, const float* __restrict__ bk,
    const float* __restrict__ Wv, const float* __restrict__ bv,
    bf16* __restrict__ Qo, bf16* __restrict__ Ko, bf16* __restrict__ Vt) {
  const int z = blockIdx.z;
  const float* W    = (z == 0) ? Wq : (z == 1) ? Wk : Wv;
  const float* bias = (z == 0) ? bq : (z == 1) ? bk : bv;

  __shared__ bf16 As[128 * 64];
  __shared__ bf16 Bs[128 * 64];

  const int tid  = threadIdx.x;
  const int lane = tid & 63;
  const int w    = tid >> 6;
  const int wr   = w >> 1, wc = w & 1;
  const int m0   = blockIdx.x * 128;
  const int n0   = blockIdx.y * 128;
  const int c    = lane & 15, g = lane >> 4;

  f32x4 acc[4][4];
#pragma unroll
  for (int i = 0; i < 4; ++i)
#pragma unroll
    for (int j = 0; j < 4; ++j) acc[i][j] = f32x4{0.f, 0.f, 0.f, 0.f};

  for (int k0 = 0; k0 < DD; k0 += 64) {
    __syncthreads();
#pragma unroll
    for (int it = 0; it < 4; ++it) {
      int idx = tid + it * 256;       // chunk id (chunk = 8 bf16)
      int row = idx >> 3, c8 = idx & 7;
      const f32x4* ga = (const f32x4*)(X + (size_t)(m0 + row) * DD + k0 + c8 * 8);
      f32x4 a0 = ga[0], a1 = ga[1];
      *(bf16x8*)(&As[row * 64 + ((c8 * 8) ^ ((row & 7) << 3))]) = cvt8(a0, a1);
      const f32x4* gb = (const f32x4*)(W + (size_t)(n0 + row) * DD + k0 + c8 * 8);
      f32x4 b0 = gb[0], b1 = gb[1];
      *(bf16x8*)(&Bs[row * 64 + ((c8 * 8) ^ ((row & 7) << 3))]) = cvt8(b0, b1);
    }
    __syncthreads();

#pragma unroll
    for (int kk = 0; kk < 64; kk += 32) {
      bf16x8 af[4], bfr[4];
#pragma unroll
      for (int m = 0; m < 4; ++m) {
        int row = wr * 64 + m * 16 + c;
        af[m] = *(const bf16x8*)(&As[row * 64 + ((kk + g * 8) ^ ((row & 7) << 3))]);
      }
#pragma unroll
      for (int n = 0; n < 4; ++n) {
        int row = wc * 64 + n * 16 + c;
        bfr[n] = *(const bf16x8*)(&Bs[row * 64 + ((kk + g * 8) ^ ((row & 7) << 3))]);
      }
#pragma unroll
      for (int m = 0; m < 4; ++m)
#pragma unroll
        for (int n = 0; n < 4; ++n)
          acc[m][n] = MFMA16(af[m], bfr[n], acc[m][n]);
    }
  }

#pragma unroll
  for (int n = 0; n < 4; ++n) {
    int colg = n0 + wc * 64 + n * 16 + c;
    float bv_ = bias[colg];
#pragma unroll
    for (int m = 0; m < 4; ++m) {
      int rowg = m0 + wr * 64 + m * 16 + g * 4;
      f32x4 a = acc[m][n];
      if (z < 2) {
        bf16* dst = (z == 0) ? Qo : Ko;
#pragma unroll
        for (int j = 0; j < 4; ++j)
          dst[(size_t)(rowg + j) * DD + colg] = (bf16)(a[j] + bv_);
      } else {
        int bi = rowg >> 11, s = rowg & 2047;
        int hh = colg >> 6, dd = colg & 63;
        bf16x4 pv;
#pragma unroll
        for (int j = 0; j < 4; ++j) pv[j] = (bf16)(a[j] + bv_);
        *(bf16x4*)(&Vt[(((size_t)bi * HH + hh) * HD + dd) * SS + s]) = pv;
      }
    }
  }
}

// ---------------------------------------------------------------------------
// Kernel 2: flash attention, 32x32x16 MFMA. Grid (B*H, S/128), 4 waves.
// Wave w owns q rows [qb*128 + w*32, +32).  Per-lane: q = lane&31, hi=lane>>5.
// Mask row (pre-scaled by log2e) lives in LDS: per-tile mask reads are
// broadcast ds_reads (lgkm), so the only vmcnt wait per tile is the ds_write
// of the prefetched K/V tile -> stage loads overlap the whole tile compute.
// NO launch_bounds min-waves arg: at ~108 VGPR the HW gives 4 waves/SIMD
// naturally; forcing it capped VGPR=64 and spilled (R5: FETCH 41->950 MB).
// ---------------------------------------------------------------------------
__global__ __launch_bounds__(256) void attn(
    const bf16* __restrict__ Q,   // [B*S, D]
    const bf16* __restrict__ K,   // [B*S, D]
    const bf16* __restrict__ Vt,  // [(b*16+h)*64 + d][S]
    const float* __restrict__ mask,  // [B, S] additive
    float* __restrict__ out) {       // [B, S, D] fp32
  __shared__ bf16 Ks[2][64 * 64];
  __shared__ bf16 Vs[2][64 * 64];
  __shared__ float Ms[SS];   // mask * log2e

  const int bh = blockIdx.x;  // 0..63
  const int qb = blockIdx.y;  // 0..15
  const int b = bh >> 4, h = bh & 15;
  const int tid = threadIdx.x;
  const int lane = tid & 63;
  const int w = tid >> 6;
  const int l31 = lane & 31, hi = lane >> 5;
  const int hi4 = hi * 4, hi8 = hi * 8;
  const int qg = qb * 128 + w * 32 + l31;  // this lane's q row

  const bf16* qptr = Q + ((size_t)(b * SS + qg)) * DD + h * HD;
  bf16x8 qB[4];
#pragma unroll
  for (int ks = 0; ks < 4; ++ks)
    qB[ks] = *(const bf16x8*)(qptr + ks * 16 + hi8);

  const bf16* Kbase = K + ((size_t)b * SS) * DD + h * HD;
  const bf16* Vbase = Vt + ((size_t)bh * HD) * SS;

  const int srow = lane >> 3;
  const int sj   = lane & 7;
  const int r0   = w * 16 + srow, r1 = r0 + 8;
  const int swz0 = r0 * 64 + ((sj ^ (r0 & 7)) * 8);
  const int swz1 = r1 * 64 + ((sj ^ (r1 & 7)) * 8);

  f32x4 lacc = {0.f, 0.f, 0.f, 0.f};
  f32x16 acc[2] = {};

  bf16x8 stK0, stK1, stV0, stV1;

  // ---- prologue: mask row -> LDS (pre-scaled), stage tile 0 into buf 0 ----
  {
    const float* mbase = mask + b * SS;
    f32x4 m0 = *(const f32x4*)(mbase + tid * 8);
    f32x4 m1 = *(const f32x4*)(mbase + tid * 8 + 4);
    *(f32x4*)(&Ms[tid * 8])     = m0 * LOG2E;
    *(f32x4*)(&Ms[tid * 8 + 4]) = m1 * LOG2E;
  }
  stK0 = *(const bf16x8*)(Kbase + (size_t)r0 * DD + sj * 8);
  stK1 = *(const bf16x8*)(Kbase + (size_t)r1 * DD + sj * 8);
  stV0 = *(const bf16x8*)(Vbase + (size_t)r0 * SS + sj * 8);
  stV1 = *(const bf16x8*)(Vbase + (size_t)r1 * SS + sj * 8);
  *(bf16x8*)(&Ks[0][swz0]) = stK0;
  *(bf16x8*)(&Ks[0][swz1]) = stK1;
  *(bf16x8*)(&Vs[0][swz0]) = stV0;
  *(bf16x8*)(&Vs[0][swz1]) = stV1;
  __syncthreads();

  for (int t2 = 0; t2 < 16; ++t2) {
#pragma unroll
    for (int half = 0; half < 2; ++half) {
      const int t = t2 * 2 + half;
      const int kv0 = t * 64;
      const bool last = (t == 31);

      // ---- issue next tile's global loads (hide under compute) ----
      if (!last) {
        const int sg = kv0 + 64;
        stK0 = *(const bf16x8*)(Kbase + (size_t)(sg + r0) * DD + sj * 8);
        stK1 = *(const bf16x8*)(Kbase + (size_t)(sg + r1) * DD + sj * 8);
        stV0 = *(const bf16x8*)(Vbase + (size_t)r0 * SS + sg + sj * 8);
        stV1 = *(const bf16x8*)(Vbase + (size_t)r1 * SS + sg + sj * 8);
      }

      // ---- QK^T: st[kvb] over 4 d-slices ----
      f32x16 st[2] = {};
      __builtin_amdgcn_s_setprio(1);
#pragma unroll
      for (int kvb = 0; kvb < 2; ++kvb) {
        const int krow = kvb * 32 + l31;
        const int kro = krow * 64, kr7 = krow & 7;
#pragma unroll
        for (int ks = 0; ks < 4; ++ks) {
          bf16x8 ka = *(const bf16x8*)(&Ks[half][kro + (((2 * ks + hi) ^ kr7) * 8)]);
          st[kvb] = MFMA32(ka, qB[ks], st[kvb]);
        }
      }
      __builtin_amdgcn_s_setprio(0);

      // ---- V^T frags (issue early; latency hides under softmax) ----
      bf16x8 va[2][4];
#pragma unroll
      for (int db = 0; db < 2; ++db) {
        const int vrow = db * 32 + l31;
        const int vro = vrow * 64, vr7 = vrow & 7;
#pragma unroll
        for (int sl = 0; sl < 4; ++sl)
          va[db][sl] = *(const bf16x8*)(&Vs[half][vro + (((2 * sl + hi) ^ vr7) * 8)]);
      }

      // ---- softmax: p = exp2(st*scale*log2e + ms), mask from LDS ----
#pragma unroll
      for (int kvb = 0; kvb < 2; ++kvb) {
#pragma unroll
        for (int rg = 0; rg < 4; ++rg) {
          f32x4 mk = *(const f32x4*)(&Ms[kv0 + kvb * 32 + rg * 8 + hi4]);
#pragma unroll
          for (int j = 0; j < 4; ++j) {
            float e = fast_exp2(fmaf(st[kvb][rg * 4 + j], SCALE_LOG2E, mk[j]));
            st[kvb][rg * 4 + j] = e;
            lacc[j] += e;
          }
        }
      }

      // ---- P repack (shfl_xor(32) + select) and PV MFMAs ----
      __builtin_amdgcn_s_setprio(1);
#pragma unroll
      for (int kvb = 0; kvb < 2; ++kvb) {
#pragma unroll
        for (int s2 = 0; s2 < 2; ++s2) {
          unsigned L0 = pack2(st[kvb][8 * s2 + 0], st[kvb][8 * s2 + 1]);
          unsigned L1 = pack2(st[kvb][8 * s2 + 2], st[kvb][8 * s2 + 3]);
          unsigned H0 = pack2(st[kvb][8 * s2 + 4], st[kvb][8 * s2 + 5]);
          unsigned H1 = pack2(st[kvb][8 * s2 + 6], st[kvb][8 * s2 + 7]);
          unsigned xL0 = (unsigned)__shfl_xor((int)L0, 32);
          unsigned xL1 = (unsigned)__shfl_xor((int)L1, 32);
          unsigned xH0 = (unsigned)__shfl_xor((int)H0, 32);
          unsigned xH1 = (unsigned)__shfl_xor((int)H1, 32);
          union { unsigned u[4]; bf16x8 v; } pb;
          pb.u[0] = hi ? xH0 : L0;   // e0,e1: own L0 / partner H0
          pb.u[1] = hi ? xH1 : L1;   // e2,e3
          pb.u[2] = hi ? H0 : xL0;   // e4,e5: partner L0 / own H0
          pb.u[3] = hi ? H1 : xL1;   // e6,e7
          const int sl = kvb * 2 + s2;
          acc[0] = MFMA32(va[0][sl], pb.v, acc[0]);
          acc[1] = MFMA32(va[1][sl], pb.v, acc[1]);
        }
      }
      __builtin_amdgcn_s_setprio(0);

      // ---- write next tile to other buffer, then barrier ----
      if (!last) {
        *(bf16x8*)(&Ks[half ^ 1][swz0]) = stK0;
        *(bf16x8*)(&Ks[half ^ 1][swz1]) = stK1;
        *(bf16x8*)(&Vs[half ^ 1][swz0]) = stV0;
        *(bf16x8*)(&Vs[half ^ 1][swz1]) = stV1;
      }
      __syncthreads();
    }
  }

  // ---- lsum: halves hold disjoint kv subsets; combine across hi ----
  float ls = lacc[0] + lacc[1] + lacc[2] + lacc[3];
  ls += __shfl_xor(ls, 32);
  const float inv = 1.0f / ls;

  // ---- store ctx[qg][d] = acc^T * inv;  d = 32db + 8rg + 4hi + j ----
  float* op = out + ((size_t)(b * SS + qg)) * DD + h * HD;
#pragma unroll
  for (int db = 0; db < 2; ++db)
#pragma unroll
    for (int rg = 0; rg < 4; ++rg) {
      f32x4 v;
#pragma unroll
      for (int j = 0; j < 4; ++j) v[j] = acc[db][rg * 4 + j] * inv;
      *(f32x4*)(op + db * 32 + rg * 8 + hi4) = v;
    }
}

// ---------------------------------------------------------------------------
extern "C" void kernel_launch(void* const* d_in, const int* in_sizes, int n_in,
                              void* d_out, int out_size, void* d_ws, size_t ws_size,
                              hipStream_t stream) {
  const float* X    = (const float*)d_in[0];
  const float* mask = (const float*)d_in[1];
  const float* Wq   = (const float*)d_in[2];
  const float* bq   = (const float*)d_in[3];
  const float* Wk   = (const float*)d_in[4];
  const float* bk   = (const float*)d_in[5];
  const float* Wv   = (const float*)d_in[6];
  const float* bv   = (const float*)d_in[7];

  bf16* Qw = (bf16*)d_ws;
  bf16* Kw = Qw + (size_t)BB * SS * DD;
  bf16* Vt = Kw + (size_t)BB * SS * DD;

  dim3 g1((BB * SS) / 128, DD / 128, 3);
  qkv_gemm<<<g1, 256, 0, stream>>>(X, Wq, bq, Wk, bk, Wv, bv, Qw, Kw, Vt);

  dim3 g2(BB * HH, SS / 128);  // 64 x 16
  attn<<<g2, 256, 0, stream>>>(Qw, Kw, Vt, mask, (float*)d_out);
}

// Round 8
// 200.843 us; speedup vs baseline: 2.9397x; 1.2538x over previous
//
#include <hip/hip_runtime.h>

// ---------------------------------------------------------------------------
// RoBERTa self-attention: QKV projection (bf16 MFMA) + flash attention.
// B=4, S=2048, D=1024, H=16, HD=64.  fp32 in/out, bf16 internal, fp32 acc.
// R7: DS-pipe diet for attn (R6 est. ~50% DS-busy):
//   (1) K/V staging via global_load_lds width=16 with pre-swizzled SOURCE
//       (linear LDS dest, m173 pattern) -- removes 4 ds_writes + 4 reg loads
//       per wave/tile.
//   (2) P repack via __builtin_amdgcn_permlane32_swap (VALU) instead of 16
//       ds_bpermute shuffles. Builtin (not raw asm -- R3's failure) returns
//       the {vdst,vsrc} pair; shfl+select fallback if unavailable.
// ---------------------------------------------------------------------------

typedef __bf16 bf16;
typedef bf16  bf16x8 __attribute__((ext_vector_type(8)));
typedef bf16  bf16x4 __attribute__((ext_vector_type(4)));
typedef float f32x4  __attribute__((ext_vector_type(4)));
typedef float f32x16 __attribute__((ext_vector_type(16)));
typedef int   i32x2  __attribute__((ext_vector_type(2)));

#define MFMA16(A, B, C) __builtin_amdgcn_mfma_f32_16x16x32_bf16((A), (B), (C), 0, 0, 0)
#define MFMA32(A, B, C) __builtin_amdgcn_mfma_f32_32x32x16_bf16((A), (B), (C), 0, 0, 0)

constexpr int BB = 4, SS = 2048, DD = 1024, HH = 16, HD = 64;
constexpr float SCALE = 0.125f;                       // 1/sqrt(64)
constexpr float LOG2E = 1.44269504088896f;
constexpr float SCALE_LOG2E = SCALE * LOG2E;

__device__ __forceinline__ float fast_exp2(float x) {
#if __has_builtin(__builtin_amdgcn_exp2f)
  return __builtin_amdgcn_exp2f(x);
#else
  return exp2f(x);
#endif
}

__device__ __forceinline__ bf16x8 cvt8(f32x4 a, f32x4 b) {
  bf16x8 r;
  r[0] = (bf16)a[0]; r[1] = (bf16)a[1]; r[2] = (bf16)a[2]; r[3] = (bf16)a[3];
  r[4] = (bf16)b[0]; r[5] = (bf16)b[1]; r[6] = (bf16)b[2]; r[7] = (bf16)b[3];
  return r;
}

__device__ __forceinline__ unsigned pack2(float lo, float hi) {
  union { bf16 h[2]; unsigned u; } r;
  r.h[0] = (bf16)lo; r.h[1] = (bf16)hi;
  return r.u;
}

// Exchange across the wave's 32-lane halves: post-state
//   a = (hi ? partner_b : own_a), b = (hi ? own_b : partner_a)
__device__ __forceinline__ void swap32(unsigned &a, unsigned &b) {
#if __has_builtin(__builtin_amdgcn_permlane32_swap)
  i32x2 r = __builtin_amdgcn_permlane32_swap((int)a, (int)b, false, false);
  a = (unsigned)r[0]; b = (unsigned)r[1];
#else
  int hi = (int)((threadIdx.x >> 5) & 1);
  unsigned xa = (unsigned)__shfl_xor((int)a, 32);
  unsigned xb = (unsigned)__shfl_xor((int)b, 32);
  unsigned na = hi ? xb : a;
  unsigned nb = hi ? b  : xa;
  a = na; b = nb;
#endif
}

// async global -> LDS, 16B per lane (dest = uniform base + lane*16)
__device__ __forceinline__ void gload_lds16(const bf16* g, bf16* l) {
  __builtin_amdgcn_global_load_lds(
      (const __attribute__((address_space(1))) void*)g,
      (__attribute__((address_space(3))) void*)l, 16, 0, 0);
}

// ---------------------------------------------------------------------------
// Kernel 1: Y = X @ W^T + b, output bf16.  (unchanged: ~63us, ~817 TF)
//   z==0 -> Q [8192,1024];  z==1 -> K [8192,1024];
//   z==2 -> V transposed per-head: Vt[(b*16+h)*64 + d][s]
// ---------------------------------------------------------------------------
__global__ __launch_bounds__(256, 2) void qkv_gemm(
    const float* __restrict__ X,
    const float* __restrict__ Wq, const float* __restrict__ bq,
    const float* __restrict__ Wk, const float* __restrict__ bk,
    const float* __restrict__ Wv, const float* __restrict__ bv,
    bf16* __restrict__ Qo, bf16* __restrict__ Ko, bf16* __restrict__ Vt) {
  const int z = blockIdx.z;
  const float* W    = (z == 0) ? Wq : (z == 1) ? Wk : Wv;
  const float* bias = (z == 0) ? bq : (z == 1) ? bk : bv;

  __shared__ bf16 As[128 * 64];
  __shared__ bf16 Bs[128 * 64];

  const int tid  = threadIdx.x;
  const int lane = tid & 63;
  const int w    = tid >> 6;
  const int wr   = w >> 1, wc = w & 1;
  const int m0   = blockIdx.x * 128;
  const int n0   = blockIdx.y * 128;
  const int c    = lane & 15, g = lane >> 4;

  f32x4 acc[4][4];
#pragma unroll
  for (int i = 0; i < 4; ++i)
#pragma unroll
    for (int j = 0; j < 4; ++j) acc[i][j] = f32x4{0.f, 0.f, 0.f, 0.f};

  for (int k0 = 0; k0 < DD; k0 += 64) {
    __syncthreads();
#pragma unroll
    for (int it = 0; it < 4; ++it) {
      int idx = tid + it * 256;       // chunk id (chunk = 8 bf16)
      int row = idx >> 3, c8 = idx & 7;
      const f32x4* ga = (const f32x4*)(X + (size_t)(m0 + row) * DD + k0 + c8 * 8);
      f32x4 a0 = ga[0], a1 = ga[1];
      *(bf16x8*)(&As[row * 64 + ((c8 * 8) ^ ((row & 7) << 3))]) = cvt8(a0, a1);
      const f32x4* gb = (const f32x4*)(W + (size_t)(n0 + row) * DD + k0 + c8 * 8);
      f32x4 b0 = gb[0], b1 = gb[1];
      *(bf16x8*)(&Bs[row * 64 + ((c8 * 8) ^ ((row & 7) << 3))]) = cvt8(b0, b1);
    }
    __syncthreads();

#pragma unroll
    for (int kk = 0; kk < 64; kk += 32) {
      bf16x8 af[4], bfr[4];
#pragma unroll
      for (int m = 0; m < 4; ++m) {
        int row = wr * 64 + m * 16 + c;
        af[m] = *(const bf16x8*)(&As[row * 64 + ((kk + g * 8) ^ ((row & 7) << 3))]);
      }
#pragma unroll
      for (int n = 0; n < 4; ++n) {
        int row = wc * 64 + n * 16 + c;
        bfr[n] = *(const bf16x8*)(&Bs[row * 64 + ((kk + g * 8) ^ ((row & 7) << 3))]);
      }
#pragma unroll
      for (int m = 0; m < 4; ++m)
#pragma unroll
        for (int n = 0; n < 4; ++n)
          acc[m][n] = MFMA16(af[m], bfr[n], acc[m][n]);
    }
  }

#pragma unroll
  for (int n = 0; n < 4; ++n) {
    int colg = n0 + wc * 64 + n * 16 + c;
    float bv_ = bias[colg];
#pragma unroll
    for (int m = 0; m < 4; ++m) {
      int rowg = m0 + wr * 64 + m * 16 + g * 4;
      f32x4 a = acc[m][n];
      if (z < 2) {
        bf16* dst = (z == 0) ? Qo : Ko;
#pragma unroll
        for (int j = 0; j < 4; ++j)
          dst[(size_t)(rowg + j) * DD + colg] = (bf16)(a[j] + bv_);
      } else {
        int bi = rowg >> 11, s = rowg & 2047;
        int hh = colg >> 6, dd = colg & 63;
        bf16x4 pv;
#pragma unroll
        for (int j = 0; j < 4; ++j) pv[j] = (bf16)(a[j] + bv_);
        *(bf16x4*)(&Vt[(((size_t)bi * HH + hh) * HD + dd) * SS + s]) = pv;
      }
    }
  }
}

// ---------------------------------------------------------------------------
// Kernel 2: flash attention, 32x32x16 MFMA. Grid (B*H, S/128), 4 waves.
// Wave w owns q rows [qb*128 + w*32, +32).  Per-lane: q = lane&31, hi=lane>>5.
// K/V tiles staged with global_load_lds (linear LDS dest, pre-swizzled global
// source: slot j of row r holds global chunk j^(r&7), matching the XOR read).
// Mask (pre-scaled by log2e) in LDS, broadcast reads. Repack via permlane.
// ---------------------------------------------------------------------------
__global__ __launch_bounds__(256) void attn(
    const bf16* __restrict__ Q,   // [B*S, D]
    const bf16* __restrict__ K,   // [B*S, D]
    const bf16* __restrict__ Vt,  // [(b*16+h)*64 + d][S]
    const float* __restrict__ mask,  // [B, S] additive
    float* __restrict__ out) {       // [B, S, D] fp32
  __shared__ bf16 Ks[2][64 * 64];
  __shared__ bf16 Vs[2][64 * 64];
  __shared__ float Ms[SS];   // mask * log2e

  const int bh = blockIdx.x;  // 0..63
  const int qb = blockIdx.y;  // 0..15
  const int b = bh >> 4, h = bh & 15;
  const int tid = threadIdx.x;
  const int lane = tid & 63;
  const int w = tid >> 6;
  const int l31 = lane & 31, hi = lane >> 5;
  const int hi4 = hi * 4, hi8 = hi * 8;
  const int qg = qb * 128 + w * 32 + l31;  // this lane's q row

  const bf16* qptr = Q + ((size_t)(b * SS + qg)) * DD + h * HD;
  bf16x8 qB[4];
#pragma unroll
  for (int ks = 0; ks < 4; ++ks)
    qB[ks] = *(const bf16x8*)(qptr + ks * 16 + hi8);

  const bf16* Kbase = K + ((size_t)b * SS) * DD + h * HD;
  const bf16* Vbase = Vt + ((size_t)bh * HD) * SS;

  // staging geometry: call covers 8 rows x 8 chunks; lane -> row base+lr,
  // source chunk (lane&7)^lr so that LDS slot j holds global chunk j^(r&7).
  const int lr = lane >> 3;                 // 0..7
  const int lc = ((lane & 7) ^ lr) * 8;     // pre-swizzled chunk elem offset
  const int r0 = w * 16 + lr;               // rows for call A (call B: +8)
  const int dbase0 = (w * 16) * 64;         // linear LDS dest (uniform/wave)
  const int dbase1 = (w * 16 + 8) * 64;

  f32x4 lacc = {0.f, 0.f, 0.f, 0.f};
  f32x16 acc[2] = {};

  // ---- prologue: mask -> LDS (pre-scaled); stage tile 0 into buf 0 ----
  {
    const float* mbase = mask + b * SS;
    f32x4 m0 = *(const f32x4*)(mbase + tid * 8);
    f32x4 m1 = *(const f32x4*)(mbase + tid * 8 + 4);
    *(f32x4*)(&Ms[tid * 8])     = m0 * LOG2E;
    *(f32x4*)(&Ms[tid * 8 + 4]) = m1 * LOG2E;
  }
  gload_lds16(Kbase + (size_t)r0 * DD + lc,       &Ks[0][dbase0]);
  gload_lds16(Kbase + (size_t)(r0 + 8) * DD + lc, &Ks[0][dbase1]);
  gload_lds16(Vbase + (size_t)r0 * SS + lc,       &Vs[0][dbase0]);
  gload_lds16(Vbase + (size_t)(r0 + 8) * SS + lc, &Vs[0][dbase1]);
  __syncthreads();

  for (int t2 = 0; t2 < 16; ++t2) {
#pragma unroll
    for (int half = 0; half < 2; ++half) {
      const int t = t2 * 2 + half;
      const int kv0 = t * 64;
      const bool last = (t == 31);

      // ---- prefetch next tile direct to LDS (async, drains at barrier) ----
      if (!last) {
        const int sg = kv0 + 64;
        const int nb = half ^ 1;
        gload_lds16(Kbase + (size_t)(sg + r0) * DD + lc,       &Ks[nb][dbase0]);
        gload_lds16(Kbase + (size_t)(sg + r0 + 8) * DD + lc,   &Ks[nb][dbase1]);
        gload_lds16(Vbase + (size_t)r0 * SS + sg + lc,         &Vs[nb][dbase0]);
        gload_lds16(Vbase + (size_t)(r0 + 8) * SS + sg + lc,   &Vs[nb][dbase1]);
      }

      // ---- QK^T: st[kvb] over 4 d-slices ----
      f32x16 st[2] = {};
      __builtin_amdgcn_s_setprio(1);
#pragma unroll
      for (int kvb = 0; kvb < 2; ++kvb) {
        const int krow = kvb * 32 + l31;
        const int kro = krow * 64, kr7 = krow & 7;
#pragma unroll
        for (int ks = 0; ks < 4; ++ks) {
          bf16x8 ka = *(const bf16x8*)(&Ks[half][kro + (((2 * ks + hi) ^ kr7) * 8)]);
          st[kvb] = MFMA32(ka, qB[ks], st[kvb]);
        }
      }
      __builtin_amdgcn_s_setprio(0);

      // ---- V^T frags ----
      bf16x8 va[2][4];
#pragma unroll
      for (int db = 0; db < 2; ++db) {
        const int vrow = db * 32 + l31;
        const int vro = vrow * 64, vr7 = vrow & 7;
#pragma unroll
        for (int sl = 0; sl < 4; ++sl)
          va[db][sl] = *(const bf16x8*)(&Vs[half][vro + (((2 * sl + hi) ^ vr7) * 8)]);
      }

      // ---- softmax: p = exp2(st*scale*log2e + ms), mask from LDS ----
#pragma unroll
      for (int kvb = 0; kvb < 2; ++kvb) {
#pragma unroll
        for (int rg = 0; rg < 4; ++rg) {
          f32x4 mk = *(const f32x4*)(&Ms[kv0 + kvb * 32 + rg * 8 + hi4]);
#pragma unroll
          for (int j = 0; j < 4; ++j) {
            float e = fast_exp2(fmaf(st[kvb][rg * 4 + j], SCALE_LOG2E, mk[j]));
            st[kvb][rg * 4 + j] = e;
            lacc[j] += e;
          }
        }
      }

      // ---- P repack (pack + permlane32_swap) and PV MFMAs ----
      __builtin_amdgcn_s_setprio(1);
#pragma unroll
      for (int kvb = 0; kvb < 2; ++kvb) {
#pragma unroll
        for (int s2 = 0; s2 < 2; ++s2) {
          unsigned L0 = pack2(st[kvb][8 * s2 + 0], st[kvb][8 * s2 + 1]);
          unsigned L1 = pack2(st[kvb][8 * s2 + 2], st[kvb][8 * s2 + 3]);
          unsigned H0 = pack2(st[kvb][8 * s2 + 4], st[kvb][8 * s2 + 5]);
          unsigned H1 = pack2(st[kvb][8 * s2 + 6], st[kvb][8 * s2 + 7]);
          swap32(L0, H0);   // post: L0 = own-lo/partner-hi, H0 = partner-lo/own-hi
          swap32(L1, H1);
          union { unsigned u[4]; bf16x8 v; } pb;
          pb.u[0] = L0; pb.u[1] = L1; pb.u[2] = H0; pb.u[3] = H1;
          const int sl = kvb * 2 + s2;
          acc[0] = MFMA32(va[0][sl], pb.v, acc[0]);
          acc[1] = MFMA32(va[1][sl], pb.v, acc[1]);
        }
      }
      __builtin_amdgcn_s_setprio(0);

      __syncthreads();  // vmcnt(0)+lgkmcnt(0) drain: prefetched tile ready
    }
  }

  // ---- lsum: halves hold disjoint kv subsets; combine across hi ----
  float ls = lacc[0] + lacc[1] + lacc[2] + lacc[3];
  ls += __shfl_xor(ls, 32);
  const float inv = 1.0f / ls;

  // ---- store ctx[qg][d] = acc^T * inv;  d = 32db + 8rg + 4hi + j ----
  float* op = out + ((size_t)(b * SS + qg)) * DD + h * HD;
#pragma unroll
  for (int db = 0; db < 2; ++db)
#pragma unroll
    for (int rg = 0; rg < 4; ++rg) {
      f32x4 v;
#pragma unroll
      for (int j = 0; j < 4; ++j) v[j] = acc[db][rg * 4 + j] * inv;
      *(f32x4*)(op + db * 32 + rg * 8 + hi4) = v;
    }
}

// ---------------------------------------------------------------------------
extern "C" void kernel_launch(void* const* d_in, const int* in_sizes, int n_in,
                              void* d_out, int out_size, void* d_ws, size_t ws_size,
                              hipStream_t stream) {
  const float* X    = (const float*)d_in[0];
  const float* mask = (const float*)d_in[1];
  const float* Wq   = (const float*)d_in[2];
  const float* bq   = (const float*)d_in[3];
  const float* Wk   = (const float*)d_in[4];
  const float* bk   = (const float*)d_in[5];
  const float* Wv   = (const float*)d_in[6];
  const float* bv   = (const float*)d_in[7];

  bf16* Qw = (bf16*)d_ws;
  bf16* Kw = Qw + (size_t)BB * SS * DD;
  bf16* Vt = Kw + (size_t)BB * SS * DD;

  dim3 g1((BB * SS) / 128, DD / 128, 3);
  qkv_gemm<<<g1, 256, 0, stream>>>(X, Wq, bq, Wk, bk, Wv, bv, Qw, Kw, Vt);

  dim3 g2(BB * HH, SS / 128);  // 64 x 16
  attn<<<g2, 256, 0, stream>>>(Qw, Kw, Vt, mask, (float*)d_out);
}

// Round 9
// 166.618 us; speedup vs baseline: 3.5436x; 1.2054x over previous
//
#include <hip/hip_runtime.h>

// ---------------------------------------------------------------------------
// RoBERTa self-attention: QKV projection (bf16 MFMA) + flash attention.
// B=4, S=2048, D=1024, H=16, HD=64.  fp32 in/out, bf16 internal, fp32 acc.
// R8: (a) attn VALU diet: precomputed swizzle offsets (imm-folded ds_reads),
//     mask preloaded as QK^T C-operand (kills per-tile zero-init+fma),
//     incremental staging pointers. R7 showed VALUBusy 55% dominated by
//     addressing, not math.
//     (b) qkv: X/W pre-converted to bf16 (scratch in d_out -- attn overwrites
//     it later), staging via global_load_lds (m97 874-TF structure); R7's
//     cvt-in-staging path was latency-exposed (all counters low).
// ---------------------------------------------------------------------------

typedef __bf16 bf16;
typedef bf16  bf16x8 __attribute__((ext_vector_type(8)));
typedef bf16  bf16x4 __attribute__((ext_vector_type(4)));
typedef float f32x4  __attribute__((ext_vector_type(4)));
typedef float f32x16 __attribute__((ext_vector_type(16)));
typedef int   i32x2  __attribute__((ext_vector_type(2)));

#define MFMA16(A, B, C) __builtin_amdgcn_mfma_f32_16x16x32_bf16((A), (B), (C), 0, 0, 0)
#define MFMA32(A, B, C) __builtin_amdgcn_mfma_f32_32x32x16_bf16((A), (B), (C), 0, 0, 0)

constexpr int BB = 4, SS = 2048, DD = 1024, HH = 16, HD = 64;
constexpr int NX = BB * SS * DD;   // 8388608
constexpr int NW = DD * DD;        // 1048576
constexpr float SCALE = 0.125f;    // 1/sqrt(64)
constexpr float LOG2E = 1.44269504088896f;
constexpr float SCALE_LOG2E = SCALE * LOG2E;

__device__ __forceinline__ float fast_exp2(float x) {
#if __has_builtin(__builtin_amdgcn_exp2f)
  return __builtin_amdgcn_exp2f(x);
#else
  return exp2f(x);
#endif
}

__device__ __forceinline__ bf16x8 cvt8(f32x4 a, f32x4 b) {
  bf16x8 r;
  r[0] = (bf16)a[0]; r[1] = (bf16)a[1]; r[2] = (bf16)a[2]; r[3] = (bf16)a[3];
  r[4] = (bf16)b[0]; r[5] = (bf16)b[1]; r[6] = (bf16)b[2]; r[7] = (bf16)b[3];
  return r;
}

__device__ __forceinline__ unsigned pack2(float lo, float hi) {
  union { bf16 h[2]; unsigned u; } r;
  r.h[0] = (bf16)lo; r.h[1] = (bf16)hi;
  return r.u;
}

// Exchange across the wave's 32-lane halves (verified R7).
__device__ __forceinline__ void swap32(unsigned &a, unsigned &b) {
#if __has_builtin(__builtin_amdgcn_permlane32_swap)
  i32x2 r = __builtin_amdgcn_permlane32_swap((int)a, (int)b, false, false);
  a = (unsigned)r[0]; b = (unsigned)r[1];
#else
  int hi = (int)((threadIdx.x >> 5) & 1);
  unsigned xa = (unsigned)__shfl_xor((int)a, 32);
  unsigned xb = (unsigned)__shfl_xor((int)b, 32);
  unsigned na = hi ? xb : a;
  unsigned nb = hi ? b  : xa;
  a = na; b = nb;
#endif
}

// async global -> LDS, 16B per lane (dest = uniform base + lane*16)
__device__ __forceinline__ void gload_lds16(const bf16* g, bf16* l) {
  __builtin_amdgcn_global_load_lds(
      (const __attribute__((address_space(1))) void*)g,
      (__attribute__((address_space(3))) void*)l, 16, 0, 0);
}

// ---------------------------------------------------------------------------
// Kernel 0: fp32 -> bf16 convert of X and Wq|Wk|Wv (into d_out scratch).
// 11.5M elems, 8 per thread; all range boundaries are wave-aligned.
// ---------------------------------------------------------------------------
__global__ __launch_bounds__(256) void cvt_bf16(
    const float* __restrict__ X,  const float* __restrict__ Wq,
    const float* __restrict__ Wk, const float* __restrict__ Wv,
    bf16* __restrict__ Xb, bf16* __restrict__ Wb) {
  int i = (blockIdx.x * 256 + threadIdx.x) * 8;
  const float* src; bf16* dst; int off;
  if (i < NX)               { src = X;  dst = Xb;          off = i; }
  else if (i < NX + NW)     { src = Wq; dst = Wb;          off = i - NX; }
  else if (i < NX + 2 * NW) { src = Wk; dst = Wb + NW;     off = i - NX - NW; }
  else                      { src = Wv; dst = Wb + 2 * NW; off = i - NX - 2 * NW; }
  f32x4 a = *(const f32x4*)(src + off);
  f32x4 b = *(const f32x4*)(src + off + 4);
  *(bf16x8*)(dst + off) = cvt8(a, b);
}

// ---------------------------------------------------------------------------
// Kernel 1: Y = Xb @ Wb[z]^T + b, bf16 in, bf16 out (m97 structure: 128x128
// tile, BK=64, global_load_lds staging with pre-swizzled source).
//   z==0 -> Q [8192,1024];  z==1 -> K;  z==2 -> V transposed per-head.
// ---------------------------------------------------------------------------
__global__ __launch_bounds__(256, 2) void qkv_gemm(
    const bf16* __restrict__ Xb, const bf16* __restrict__ Wb,
    const float* __restrict__ bq, const float* __restrict__ bk,
    const float* __restrict__ bv,
    bf16* __restrict__ Qo, bf16* __restrict__ Ko, bf16* __restrict__ Vt) {
  const int z = blockIdx.z;
  const bf16*  W    = Wb + (size_t)z * NW;
  const float* bias = (z == 0) ? bq : (z == 1) ? bk : bv;

  __shared__ bf16 As[128 * 64];
  __shared__ bf16 Bs[128 * 64];

  const int tid  = threadIdx.x;
  const int lane = tid & 63;
  const int w    = tid >> 6;
  const int wr   = w >> 1, wc = w & 1;
  const int m0   = blockIdx.x * 128;
  const int n0   = blockIdx.y * 128;
  const int c    = lane & 15, g = lane >> 4;

  // staging: wave w covers rows [w*32, +32) of each tile in 4 calls of 8 rows.
  // lane -> row lr=lane>>3, slot lane&7; source chunk (lane&7)^lr so that LDS
  // slot j of row r holds global chunk j^(r&7) (matches XOR-swizzled reads).
  const int lr  = lane >> 3;
  const int lcs = ((lane & 7) ^ lr) * 8;
  const bf16* aSrc = Xb + (size_t)(m0 + w * 32 + lr) * DD + lcs;
  const bf16* bSrc = W  + (size_t)(n0 + w * 32 + lr) * DD + lcs;
  bf16* aDst = &As[(w * 32) * 64];
  bf16* bDst = &Bs[(w * 32) * 64];

  f32x4 acc[4][4];
#pragma unroll
  for (int i = 0; i < 4; ++i)
#pragma unroll
    for (int j = 0; j < 4; ++j) acc[i][j] = f32x4{0.f, 0.f, 0.f, 0.f};

  for (int k0 = 0; k0 < DD; k0 += 64) {
    __syncthreads();   // previous compute done (WAR on LDS)
#pragma unroll
    for (int cc = 0; cc < 4; ++cc) {
      gload_lds16(aSrc + (size_t)cc * 8 * DD + k0, aDst + cc * 512);
      gload_lds16(bSrc + (size_t)cc * 8 * DD + k0, bDst + cc * 512);
    }
    __syncthreads();   // drains vmcnt: tile ready

#pragma unroll
    for (int kk = 0; kk < 64; kk += 32) {
      bf16x8 af[4], bfr[4];
#pragma unroll
      for (int m = 0; m < 4; ++m) {
        int row = wr * 64 + m * 16 + c;
        af[m] = *(const bf16x8*)(&As[row * 64 + (((kk >> 3) + g) ^ (row & 7)) * 8]);
      }
#pragma unroll
      for (int n = 0; n < 4; ++n) {
        int row = wc * 64 + n * 16 + c;
        bfr[n] = *(const bf16x8*)(&Bs[row * 64 + (((kk >> 3) + g) ^ (row & 7)) * 8]);
      }
#pragma unroll
      for (int m = 0; m < 4; ++m)
#pragma unroll
        for (int n = 0; n < 4; ++n)
          acc[m][n] = MFMA16(af[m], bfr[n], acc[m][n]);
    }
  }

#pragma unroll
  for (int n = 0; n < 4; ++n) {
    int colg = n0 + wc * 64 + n * 16 + c;
    float bv_ = bias[colg];
#pragma unroll
    for (int m = 0; m < 4; ++m) {
      int rowg = m0 + wr * 64 + m * 16 + g * 4;
      f32x4 a = acc[m][n];
      if (z < 2) {
        bf16* dst = (z == 0) ? Qo : Ko;
#pragma unroll
        for (int j = 0; j < 4; ++j)
          dst[(size_t)(rowg + j) * DD + colg] = (bf16)(a[j] + bv_);
      } else {
        int bi = rowg >> 11, s = rowg & 2047;
        int hh = colg >> 6, dd = colg & 63;
        bf16x4 pv;
#pragma unroll
        for (int j = 0; j < 4; ++j) pv[j] = (bf16)(a[j] + bv_);
        *(bf16x4*)(&Vt[(((size_t)bi * HH + hh) * HD + dd) * SS + s]) = pv;
      }
    }
  }
}

// ---------------------------------------------------------------------------
// Kernel 2: flash attention, 32x32x16 MFMA. Grid (B*H, S/128), 4 waves.
// LDS map (one 40KB block): Ks[2] @0 (2x8KB), Vs[2] @16384, Ms @32768 (8KB).
// Ms holds mask*8 ( = mask/SCALE ) and is loaded directly as the QK^T
// C-operand; p = exp2(st * SCALE*log2e).
// All fragment ds_reads use 4 precomputed per-lane byte offsets; kvb/db/half
// select via immediate offsets. Staging via global_load_lds with incremental
// pointers (K += 128KB, V += 128B per tile).
// ---------------------------------------------------------------------------
__global__ __launch_bounds__(256) void attn(
    const bf16* __restrict__ Q,   // [B*S, D]
    const bf16* __restrict__ K,   // [B*S, D]
    const bf16* __restrict__ Vt,  // [(b*16+h)*64 + d][S]
    const float* __restrict__ mask,  // [B, S] additive
    float* __restrict__ out) {       // [B, S, D] fp32
  __shared__ __align__(16) char smem[40960];

  const int bh = blockIdx.x;  // 0..63
  const int qb = blockIdx.y;  // 0..15
  const int b = bh >> 4, h = bh & 15;
  const int tid = threadIdx.x;
  const int lane = tid & 63;
  const int w = tid >> 6;
  const int l31 = lane & 31, hi = lane >> 5;
  const int hi4 = hi * 4, hi8 = hi * 8;
  const int qg = qb * 128 + w * 32 + l31;  // this lane's q row

  const bf16* qptr = Q + ((size_t)(b * SS + qg)) * DD + h * HD;
  bf16x8 qB[4];
#pragma unroll
  for (int ks = 0; ks < 4; ++ks)
    qB[ks] = *(const bf16x8*)(qptr + ks * 16 + hi8);

  // 4 shared fragment offsets (bytes): row part + XOR-permuted chunk.
  int off[4];
#pragma unroll
  for (int x = 0; x < 4; ++x)
    off[x] = l31 * 128 + (((2 * x + hi) ^ (l31 & 7)) * 16);

  // staging geometry (global_load_lds): 8 rows x 8 slots per call.
  const int lr  = lane >> 3;
  const int lc  = ((lane & 7) ^ lr) * 8;   // pre-swizzled source chunk
  const int r0  = w * 16 + lr;
  const bf16* kpA = K  + ((size_t)b * SS + r0) * DD + h * HD + lc;
  const bf16* kpB = kpA + (size_t)8 * DD;
  const bf16* vpA = Vt + ((size_t)bh * HD + r0) * SS + lc;
  const bf16* vpB = vpA + (size_t)8 * SS;
  // LDS dests (uniform per wave): K buf n at n*8192 + w*2048; V at +16384.
  bf16* kD0 = (bf16*)(smem + w * 2048);
  bf16* vD0 = (bf16*)(smem + 16384 + w * 2048);

  f32x4 lacc = {0.f, 0.f, 0.f, 0.f};
  f32x16 acc[2] = {};

  // ---- prologue: mask*8 -> Ms; stage tile 0 into buf 0 ----
  {
    const float* mbase = mask + b * SS;
    f32x4 m0 = *(const f32x4*)(mbase + tid * 8);
    f32x4 m1 = *(const f32x4*)(mbase + tid * 8 + 4);
    *(f32x4*)(smem + 32768 + tid * 32)      = m0 * 8.0f;
    *(f32x4*)(smem + 32768 + tid * 32 + 16) = m1 * 8.0f;
  }
  gload_lds16(kpA, kD0);
  gload_lds16(kpB, kD0 + 512);
  gload_lds16(vpA, vD0);
  gload_lds16(vpB, vD0 + 512);
  kpA += (size_t)64 * DD; kpB += (size_t)64 * DD;
  vpA += 64;              vpB += 64;
  __syncthreads();

  for (int t2 = 0; t2 < 16; ++t2) {
#pragma unroll
    for (int half = 0; half < 2; ++half) {
      const int t = t2 * 2 + half;
      const bool last = (t == 31);

      // ---- prefetch tile t+1 into buffer half^1 (async) ----
      if (!last) {
        bf16* kD = (bf16*)(smem + (half ^ 1) * 8192 + w * 2048);
        bf16* vD = (bf16*)(smem + 16384 + (half ^ 1) * 8192 + w * 2048);
        gload_lds16(kpA, kD);
        gload_lds16(kpB, kD + 512);
        gload_lds16(vpA, vD);
        gload_lds16(vpB, vD + 512);
        kpA += (size_t)64 * DD; kpB += (size_t)64 * DD;
        vpA += 64;              vpB += 64;
      }

      // ---- QK^T with mask/SCALE as C-operand ----
      const char* mb = smem + (t * 256 + hi4 * 4);
      union { f32x16 v; f32x4 q[4]; } st[2];
#pragma unroll
      for (int kvb = 0; kvb < 2; ++kvb)
#pragma unroll
        for (int rg = 0; rg < 4; ++rg)
          st[kvb].q[rg] = *(const f32x4*)(mb + 32768 + kvb * 128 + rg * 32);

      __builtin_amdgcn_s_setprio(1);
#pragma unroll
      for (int kvb = 0; kvb < 2; ++kvb) {
#pragma unroll
        for (int ks = 0; ks < 4; ++ks) {
          bf16x8 ka = *(const bf16x8*)(smem + off[ks] + kvb * 4096 + half * 8192);
          st[kvb].v = MFMA32(ka, qB[ks], st[kvb].v);
        }
      }
      __builtin_amdgcn_s_setprio(0);

      // ---- V^T frags (issue early) ----
      bf16x8 va[2][4];
#pragma unroll
      for (int db = 0; db < 2; ++db)
#pragma unroll
        for (int sl = 0; sl < 4; ++sl)
          va[db][sl] = *(const bf16x8*)(smem + 16384 + off[sl] + db * 4096 + half * 8192);

      // ---- softmax: p = exp2(st * SCALE*log2e) ----
#pragma unroll
      for (int kvb = 0; kvb < 2; ++kvb)
#pragma unroll
        for (int r = 0; r < 16; ++r) {
          float e = fast_exp2(st[kvb].v[r] * SCALE_LOG2E);
          st[kvb].v[r] = e;
          lacc[r & 3] += e;
        }

      // ---- P repack (pack + permlane32_swap) and PV MFMAs ----
      __builtin_amdgcn_s_setprio(1);
#pragma unroll
      for (int kvb = 0; kvb < 2; ++kvb) {
#pragma unroll
        for (int s2 = 0; s2 < 2; ++s2) {
          unsigned L0 = pack2(st[kvb].v[8 * s2 + 0], st[kvb].v[8 * s2 + 1]);
          unsigned L1 = pack2(st[kvb].v[8 * s2 + 2], st[kvb].v[8 * s2 + 3]);
          unsigned H0 = pack2(st[kvb].v[8 * s2 + 4], st[kvb].v[8 * s2 + 5]);
          unsigned H1 = pack2(st[kvb].v[8 * s2 + 6], st[kvb].v[8 * s2 + 7]);
          swap32(L0, H0);
          swap32(L1, H1);
          union { unsigned u[4]; bf16x8 v; } pb;
          pb.u[0] = L0; pb.u[1] = L1; pb.u[2] = H0; pb.u[3] = H1;
          const int sl = kvb * 2 + s2;
          acc[0] = MFMA32(va[0][sl], pb.v, acc[0]);
          acc[1] = MFMA32(va[1][sl], pb.v, acc[1]);
        }
      }
      __builtin_amdgcn_s_setprio(0);

      __syncthreads();  // drains vmcnt: prefetched tile ready
    }
  }

  // ---- lsum: halves hold disjoint kv subsets; combine across hi ----
  float ls = lacc[0] + lacc[1] + lacc[2] + lacc[3];
  ls += __shfl_xor(ls, 32);
  const float inv = 1.0f / ls;

  // ---- store ctx[qg][d] = acc^T * inv;  d = 32db + 8rg + 4hi + j ----
  float* op = out + ((size_t)(b * SS + qg)) * DD + h * HD;
#pragma unroll
  for (int db = 0; db < 2; ++db)
#pragma unroll
    for (int rg = 0; rg < 4; ++rg) {
      f32x4 v;
#pragma unroll
      for (int j = 0; j < 4; ++j) v[j] = acc[db][rg * 4 + j] * inv;
      *(f32x4*)(op + db * 32 + rg * 8 + hi4) = v;
    }
}

// ---------------------------------------------------------------------------
extern "C" void kernel_launch(void* const* d_in, const int* in_sizes, int n_in,
                              void* d_out, int out_size, void* d_ws, size_t ws_size,
                              hipStream_t stream) {
  const float* X    = (const float*)d_in[0];
  const float* mask = (const float*)d_in[1];
  const float* Wq   = (const float*)d_in[2];
  const float* bq   = (const float*)d_in[3];
  const float* Wk   = (const float*)d_in[4];
  const float* bk   = (const float*)d_in[5];
  const float* Wv   = (const float*)d_in[6];
  const float* bv   = (const float*)d_in[7];

  // workspace: Q | K | Vt (bf16, 16 MiB each)
  bf16* Qw = (bf16*)d_ws;
  bf16* Kw = Qw + (size_t)NX;
  bf16* Vt = Kw + (size_t)NX;
  // bf16 scratch for converted inputs lives in d_out (32 MiB fp32): attn
  // fully overwrites d_out afterwards, and order is cvt -> qkv -> attn.
  bf16* Xb = (bf16*)d_out;            // 16 MiB
  bf16* Wb = Xb + (size_t)NX;         // 6 MiB (Wq|Wk|Wv)

  cvt_bf16<<<(NX + 3 * NW) / 2048, 256, 0, stream>>>(X, Wq, Wk, Wv, Xb, Wb);

  dim3 g1((BB * SS) / 128, DD / 128, 3);
  qkv_gemm<<<g1, 256, 0, stream>>>(Xb, Wb, bq, bk, bv, Qw, Kw, Vt);

  dim3 g2(BB * HH, SS / 128);  // 64 x 16
  attn<<<g2, 256, 0, stream>>>(Qw, Kw, Vt, mask, (float*)d_out);
}

// Round 10
// 166.017 us; speedup vs baseline: 3.5564x; 1.0036x over previous
//
#include <hip/hip_runtime.h>

// ---------------------------------------------------------------------------
// RoBERTa self-attention: QKV projection (bf16 MFMA) + flash attention.
// B=4, S=2048, D=1024, H=16, HD=64.  fp32 in/out, bf16 internal, fp32 acc.
// R9: guarantee single-instruction exp2. If __builtin_amdgcn_exp2f is absent,
//     the old fallback exp2f() expanded to __ocml_exp2_f32 (~6 instrs) --
//     enough to explain the ~5x VALU excess (57% VALUBusy) vs hand count.
//     Fallback now inline-asm v_exp_f32 (+s_nop 1 for TRANS-use hazard
//     safety, since the hazard recognizer can't classify inline asm).
// ---------------------------------------------------------------------------

typedef __bf16 bf16;
typedef bf16  bf16x8 __attribute__((ext_vector_type(8)));
typedef bf16  bf16x4 __attribute__((ext_vector_type(4)));
typedef float f32x4  __attribute__((ext_vector_type(4)));
typedef float f32x16 __attribute__((ext_vector_type(16)));
typedef int   i32x2  __attribute__((ext_vector_type(2)));

#define MFMA16(A, B, C) __builtin_amdgcn_mfma_f32_16x16x32_bf16((A), (B), (C), 0, 0, 0)
#define MFMA32(A, B, C) __builtin_amdgcn_mfma_f32_32x32x16_bf16((A), (B), (C), 0, 0, 0)

constexpr int BB = 4, SS = 2048, DD = 1024, HH = 16, HD = 64;
constexpr int NX = BB * SS * DD;   // 8388608
constexpr int NW = DD * DD;        // 1048576
constexpr float SCALE = 0.125f;    // 1/sqrt(64)
constexpr float LOG2E = 1.44269504088896f;
constexpr float SCALE_LOG2E = SCALE * LOG2E;

__device__ __forceinline__ float fast_exp2(float x) {
#if __has_builtin(__builtin_amdgcn_exp2f)
  return __builtin_amdgcn_exp2f(x);
#else
  float r;
  asm("v_exp_f32 %0, %1\n\ts_nop 1" : "=v"(r) : "v"(x));
  return r;
#endif
}

__device__ __forceinline__ bf16x8 cvt8(f32x4 a, f32x4 b) {
  bf16x8 r;
  r[0] = (bf16)a[0]; r[1] = (bf16)a[1]; r[2] = (bf16)a[2]; r[3] = (bf16)a[3];
  r[4] = (bf16)b[0]; r[5] = (bf16)b[1]; r[6] = (bf16)b[2]; r[7] = (bf16)b[3];
  return r;
}

__device__ __forceinline__ unsigned pack2(float lo, float hi) {
  union { bf16 h[2]; unsigned u; } r;
  r.h[0] = (bf16)lo; r.h[1] = (bf16)hi;
  return r.u;
}

// Exchange across the wave's 32-lane halves (verified R7).
__device__ __forceinline__ void swap32(unsigned &a, unsigned &b) {
#if __has_builtin(__builtin_amdgcn_permlane32_swap)
  i32x2 r = __builtin_amdgcn_permlane32_swap((int)a, (int)b, false, false);
  a = (unsigned)r[0]; b = (unsigned)r[1];
#else
  int hi = (int)((threadIdx.x >> 5) & 1);
  unsigned xa = (unsigned)__shfl_xor((int)a, 32);
  unsigned xb = (unsigned)__shfl_xor((int)b, 32);
  unsigned na = hi ? xb : a;
  unsigned nb = hi ? b  : xa;
  a = na; b = nb;
#endif
}

// async global -> LDS, 16B per lane (dest = uniform base + lane*16)
__device__ __forceinline__ void gload_lds16(const bf16* g, bf16* l) {
  __builtin_amdgcn_global_load_lds(
      (const __attribute__((address_space(1))) void*)g,
      (__attribute__((address_space(3))) void*)l, 16, 0, 0);
}

// ---------------------------------------------------------------------------
// Kernel 0: fp32 -> bf16 convert of X and Wq|Wk|Wv (into d_out scratch).
// ---------------------------------------------------------------------------
__global__ __launch_bounds__(256) void cvt_bf16(
    const float* __restrict__ X,  const float* __restrict__ Wq,
    const float* __restrict__ Wk, const float* __restrict__ Wv,
    bf16* __restrict__ Xb, bf16* __restrict__ Wb) {
  int i = (blockIdx.x * 256 + threadIdx.x) * 8;
  const float* src; bf16* dst; int off;
  if (i < NX)               { src = X;  dst = Xb;          off = i; }
  else if (i < NX + NW)     { src = Wq; dst = Wb;          off = i - NX; }
  else if (i < NX + 2 * NW) { src = Wk; dst = Wb + NW;     off = i - NX - NW; }
  else                      { src = Wv; dst = Wb + 2 * NW; off = i - NX - 2 * NW; }
  f32x4 a = *(const f32x4*)(src + off);
  f32x4 b = *(const f32x4*)(src + off + 4);
  *(bf16x8*)(dst + off) = cvt8(a, b);
}

// ---------------------------------------------------------------------------
// Kernel 1: Y = Xb @ Wb[z]^T + b, bf16 in, bf16 out (m97 structure).
//   z==0 -> Q [8192,1024];  z==1 -> K;  z==2 -> V transposed per-head.
// ---------------------------------------------------------------------------
__global__ __launch_bounds__(256, 2) void qkv_gemm(
    const bf16* __restrict__ Xb, const bf16* __restrict__ Wb,
    const float* __restrict__ bq, const float* __restrict__ bk,
    const float* __restrict__ bv,
    bf16* __restrict__ Qo, bf16* __restrict__ Ko, bf16* __restrict__ Vt) {
  const int z = blockIdx.z;
  const bf16*  W    = Wb + (size_t)z * NW;
  const float* bias = (z == 0) ? bq : (z == 1) ? bk : bv;

  __shared__ bf16 As[128 * 64];
  __shared__ bf16 Bs[128 * 64];

  const int tid  = threadIdx.x;
  const int lane = tid & 63;
  const int w    = tid >> 6;
  const int wr   = w >> 1, wc = w & 1;
  const int m0   = blockIdx.x * 128;
  const int n0   = blockIdx.y * 128;
  const int c    = lane & 15, g = lane >> 4;

  const int lr  = lane >> 3;
  const int lcs = ((lane & 7) ^ lr) * 8;
  const bf16* aSrc = Xb + (size_t)(m0 + w * 32 + lr) * DD + lcs;
  const bf16* bSrc = W  + (size_t)(n0 + w * 32 + lr) * DD + lcs;
  bf16* aDst = &As[(w * 32) * 64];
  bf16* bDst = &Bs[(w * 32) * 64];

  f32x4 acc[4][4];
#pragma unroll
  for (int i = 0; i < 4; ++i)
#pragma unroll
    for (int j = 0; j < 4; ++j) acc[i][j] = f32x4{0.f, 0.f, 0.f, 0.f};

  for (int k0 = 0; k0 < DD; k0 += 64) {
    __syncthreads();   // previous compute done (WAR on LDS)
#pragma unroll
    for (int cc = 0; cc < 4; ++cc) {
      gload_lds16(aSrc + (size_t)cc * 8 * DD + k0, aDst + cc * 512);
      gload_lds16(bSrc + (size_t)cc * 8 * DD + k0, bDst + cc * 512);
    }
    __syncthreads();   // drains vmcnt: tile ready

#pragma unroll
    for (int kk = 0; kk < 64; kk += 32) {
      bf16x8 af[4], bfr[4];
#pragma unroll
      for (int m = 0; m < 4; ++m) {
        int row = wr * 64 + m * 16 + c;
        af[m] = *(const bf16x8*)(&As[row * 64 + (((kk >> 3) + g) ^ (row & 7)) * 8]);
      }
#pragma unroll
      for (int n = 0; n < 4; ++n) {
        int row = wc * 64 + n * 16 + c;
        bfr[n] = *(const bf16x8*)(&Bs[row * 64 + (((kk >> 3) + g) ^ (row & 7)) * 8]);
      }
#pragma unroll
      for (int m = 0; m < 4; ++m)
#pragma unroll
        for (int n = 0; n < 4; ++n)
          acc[m][n] = MFMA16(af[m], bfr[n], acc[m][n]);
    }
  }

#pragma unroll
  for (int n = 0; n < 4; ++n) {
    int colg = n0 + wc * 64 + n * 16 + c;
    float bv_ = bias[colg];
#pragma unroll
    for (int m = 0; m < 4; ++m) {
      int rowg = m0 + wr * 64 + m * 16 + g * 4;
      f32x4 a = acc[m][n];
      if (z < 2) {
        bf16* dst = (z == 0) ? Qo : Ko;
#pragma unroll
        for (int j = 0; j < 4; ++j)
          dst[(size_t)(rowg + j) * DD + colg] = (bf16)(a[j] + bv_);
      } else {
        int bi = rowg >> 11, s = rowg & 2047;
        int hh = colg >> 6, dd = colg & 63;
        bf16x4 pv;
#pragma unroll
        for (int j = 0; j < 4; ++j) pv[j] = (bf16)(a[j] + bv_);
        *(bf16x4*)(&Vt[(((size_t)bi * HH + hh) * HD + dd) * SS + s]) = pv;
      }
    }
  }
}

// ---------------------------------------------------------------------------
// Kernel 2: flash attention, 32x32x16 MFMA. Grid (B*H, S/128), 4 waves.
// LDS map: Ks[2] @0 (2x8KB), Vs[2] @16384, Ms @32768 (8KB, mask*8 as QK^T
// C-operand). Fragment ds_reads via 4 precomputed per-lane byte offsets;
// staging via global_load_lds with incremental pointers.
// ---------------------------------------------------------------------------
__global__ __launch_bounds__(256) void attn(
    const bf16* __restrict__ Q,   // [B*S, D]
    const bf16* __restrict__ K,   // [B*S, D]
    const bf16* __restrict__ Vt,  // [(b*16+h)*64 + d][S]
    const float* __restrict__ mask,  // [B, S] additive
    float* __restrict__ out) {       // [B, S, D] fp32
  __shared__ __align__(16) char smem[40960];

  const int bh = blockIdx.x;  // 0..63
  const int qb = blockIdx.y;  // 0..15
  const int b = bh >> 4, h = bh & 15;
  const int tid = threadIdx.x;
  const int lane = tid & 63;
  const int w = tid >> 6;
  const int l31 = lane & 31, hi = lane >> 5;
  const int hi4 = hi * 4, hi8 = hi * 8;
  const int qg = qb * 128 + w * 32 + l31;  // this lane's q row

  const bf16* qptr = Q + ((size_t)(b * SS + qg)) * DD + h * HD;
  bf16x8 qB[4];
#pragma unroll
  for (int ks = 0; ks < 4; ++ks)
    qB[ks] = *(const bf16x8*)(qptr + ks * 16 + hi8);

  // 4 shared fragment offsets (bytes): row part + XOR-permuted chunk.
  int off[4];
#pragma unroll
  for (int x = 0; x < 4; ++x)
    off[x] = l31 * 128 + (((2 * x + hi) ^ (l31 & 7)) * 16);

  // staging geometry (global_load_lds): 8 rows x 8 slots per call.
  const int lr  = lane >> 3;
  const int lc  = ((lane & 7) ^ lr) * 8;   // pre-swizzled source chunk
  const int r0  = w * 16 + lr;
  const bf16* kpA = K  + ((size_t)b * SS + r0) * DD + h * HD + lc;
  const bf16* kpB = kpA + (size_t)8 * DD;
  const bf16* vpA = Vt + ((size_t)bh * HD + r0) * SS + lc;
  const bf16* vpB = vpA + (size_t)8 * SS;
  bf16* kD0 = (bf16*)(smem + w * 2048);
  bf16* vD0 = (bf16*)(smem + 16384 + w * 2048);

  f32x4 lacc = {0.f, 0.f, 0.f, 0.f};
  f32x16 acc[2] = {};

  // ---- prologue: mask*8 -> Ms; stage tile 0 into buf 0 ----
  {
    const float* mbase = mask + b * SS;
    f32x4 m0 = *(const f32x4*)(mbase + tid * 8);
    f32x4 m1 = *(const f32x4*)(mbase + tid * 8 + 4);
    *(f32x4*)(smem + 32768 + tid * 32)      = m0 * 8.0f;
    *(f32x4*)(smem + 32768 + tid * 32 + 16) = m1 * 8.0f;
  }
  gload_lds16(kpA, kD0);
  gload_lds16(kpB, kD0 + 512);
  gload_lds16(vpA, vD0);
  gload_lds16(vpB, vD0 + 512);
  kpA += (size_t)64 * DD; kpB += (size_t)64 * DD;
  vpA += 64;              vpB += 64;
  __syncthreads();

  for (int t2 = 0; t2 < 16; ++t2) {
#pragma unroll
    for (int half = 0; half < 2; ++half) {
      const int t = t2 * 2 + half;
      const bool last = (t == 31);

      // ---- prefetch tile t+1 into buffer half^1 (async) ----
      if (!last) {
        bf16* kD = (bf16*)(smem + (half ^ 1) * 8192 + w * 2048);
        bf16* vD = (bf16*)(smem + 16384 + (half ^ 1) * 8192 + w * 2048);
        gload_lds16(kpA, kD);
        gload_lds16(kpB, kD + 512);
        gload_lds16(vpA, vD);
        gload_lds16(vpB, vD + 512);
        kpA += (size_t)64 * DD; kpB += (size_t)64 * DD;
        vpA += 64;              vpB += 64;
      }

      // ---- QK^T with mask/SCALE as C-operand ----
      const char* mb = smem + (t * 256 + hi4 * 4);
      union { f32x16 v; f32x4 q[4]; } st[2];
#pragma unroll
      for (int kvb = 0; kvb < 2; ++kvb)
#pragma unroll
        for (int rg = 0; rg < 4; ++rg)
          st[kvb].q[rg] = *(const f32x4*)(mb + 32768 + kvb * 128 + rg * 32);

      __builtin_amdgcn_s_setprio(1);
#pragma unroll
      for (int kvb = 0; kvb < 2; ++kvb) {
#pragma unroll
        for (int ks = 0; ks < 4; ++ks) {
          bf16x8 ka = *(const bf16x8*)(smem + off[ks] + kvb * 4096 + half * 8192);
          st[kvb].v = MFMA32(ka, qB[ks], st[kvb].v);
        }
      }
      __builtin_amdgcn_s_setprio(0);

      // ---- V^T frags (issue early) ----
      bf16x8 va[2][4];
#pragma unroll
      for (int db = 0; db < 2; ++db)
#pragma unroll
        for (int sl = 0; sl < 4; ++sl)
          va[db][sl] = *(const bf16x8*)(smem + 16384 + off[sl] + db * 4096 + half * 8192);

      // ---- softmax: p = exp2(st * SCALE*log2e) ----
#pragma unroll
      for (int kvb = 0; kvb < 2; ++kvb)
#pragma unroll
        for (int r = 0; r < 16; ++r) {
          float e = fast_exp2(st[kvb].v[r] * SCALE_LOG2E);
          st[kvb].v[r] = e;
          lacc[r & 3] += e;
        }

      // ---- P repack (pack + permlane32_swap) and PV MFMAs ----
      __builtin_amdgcn_s_setprio(1);
#pragma unroll
      for (int kvb = 0; kvb < 2; ++kvb) {
#pragma unroll
        for (int s2 = 0; s2 < 2; ++s2) {
          unsigned L0 = pack2(st[kvb].v[8 * s2 + 0], st[kvb].v[8 * s2 + 1]);
          unsigned L1 = pack2(st[kvb].v[8 * s2 + 2], st[kvb].v[8 * s2 + 3]);
          unsigned H0 = pack2(st[kvb].v[8 * s2 + 4], st[kvb].v[8 * s2 + 5]);
          unsigned H1 = pack2(st[kvb].v[8 * s2 + 6], st[kvb].v[8 * s2 + 7]);
          swap32(L0, H0);
          swap32(L1, H1);
          union { unsigned u[4]; bf16x8 v; } pb;
          pb.u[0] = L0; pb.u[1] = L1; pb.u[2] = H0; pb.u[3] = H1;
          const int sl = kvb * 2 + s2;
          acc[0] = MFMA32(va[0][sl], pb.v, acc[0]);
          acc[1] = MFMA32(va[1][sl], pb.v, acc[1]);
        }
      }
      __builtin_amdgcn_s_setprio(0);

      __syncthreads();  // drains vmcnt: prefetched tile ready
    }
  }

  // ---- lsum: halves hold disjoint kv subsets; combine across hi ----
  float ls = lacc[0] + lacc[1] + lacc[2] + lacc[3];
  ls += __shfl_xor(ls, 32);
  const float inv = 1.0f / ls;

  // ---- store ctx[qg][d] = acc^T * inv;  d = 32db + 8rg + 4hi + j ----
  float* op = out + ((size_t)(b * SS + qg)) * DD + h * HD;
#pragma unroll
  for (int db = 0; db < 2; ++db)
#pragma unroll
    for (int rg = 0; rg < 4; ++rg) {
      f32x4 v;
#pragma unroll
      for (int j = 0; j < 4; ++j) v[j] = acc[db][rg * 4 + j] * inv;
      *(f32x4*)(op + db * 32 + rg * 8 + hi4) = v;
    }
}

// ---------------------------------------------------------------------------
extern "C" void kernel_launch(void* const* d_in, const int* in_sizes, int n_in,
                              void* d_out, int out_size, void* d_ws, size_t ws_size,
                              hipStream_t stream) {
  const float* X    = (const float*)d_in[0];
  const float* mask = (const float*)d_in[1];
  const float* Wq   = (const float*)d_in[2];
  const float* bq   = (const float*)d_in[3];
  const float* Wk   = (const float*)d_in[4];
  const float* bk   = (const float*)d_in[5];
  const float* Wv   = (const float*)d_in[6];
  const float* bv   = (const float*)d_in[7];

  // workspace: Q | K | Vt (bf16, 16 MiB each)
  bf16* Qw = (bf16*)d_ws;
  bf16* Kw = Qw + (size_t)NX;
  bf16* Vt = Kw + (size_t)NX;
  // bf16 scratch for converted inputs lives in d_out (attn overwrites later).
  bf16* Xb = (bf16*)d_out;            // 16 MiB
  bf16* Wb = Xb + (size_t)NX;         // 6 MiB (Wq|Wk|Wv)

  cvt_bf16<<<(NX + 3 * NW) / 2048, 256, 0, stream>>>(X, Wq, Wk, Wv, Xb, Wb);

  dim3 g1((BB * SS) / 128, DD / 128, 3);
  qkv_gemm<<<g1, 256, 0, stream>>>(Xb, Wb, bq, bk, bv, Qw, Kw, Vt);

  dim3 g2(BB * HH, SS / 128);  // 64 x 16
  attn<<<g2, 256, 0, stream>>>(Qw, Kw, Vt, mask, (float*)d_out);
}

// Round 12
// 162.779 us; speedup vs baseline: 3.6272x; 1.0199x over previous
//
#include <hip/hip_runtime.h>

// ---------------------------------------------------------------------------
// RoBERTa self-attention: QKV projection (bf16 MFMA) + flash attention.
// B=4, S=2048, D=1024, H=16, HD=64.  fp32 in/out, bf16 internal, fp32 acc.
// R11 FAILED the post-timing revalidation (first check passed) -- replay-
// dependent divergence. R12 bisects: REVERT the lsum-via-ones-MFMA (accL,
// back to R10's lacc+shfl) while KEEPING the pure-constant changes
// (Q pre-scaled by SCALE*LOG2E, mask*LOG2E as C-operand, bare exp2), and
// HARDENS the tile barrier with an explicit vmcnt/lgkm drain (guards a
// latent missing-drain race on the global_load_lds prefetch).
// ---------------------------------------------------------------------------

typedef __bf16 bf16;
typedef bf16  bf16x8 __attribute__((ext_vector_type(8)));
typedef bf16  bf16x4 __attribute__((ext_vector_type(4)));
typedef float f32x4  __attribute__((ext_vector_type(4)));
typedef float f32x16 __attribute__((ext_vector_type(16)));
typedef int   i32x2  __attribute__((ext_vector_type(2)));

#define MFMA16(A, B, C) __builtin_amdgcn_mfma_f32_16x16x32_bf16((A), (B), (C), 0, 0, 0)
#define MFMA32(A, B, C) __builtin_amdgcn_mfma_f32_32x32x16_bf16((A), (B), (C), 0, 0, 0)

constexpr int BB = 4, SS = 2048, DD = 1024, HH = 16, HD = 64;
constexpr int NX = BB * SS * DD;   // 8388608
constexpr int NW = DD * DD;        // 1048576
constexpr float SCALE = 0.125f;    // 1/sqrt(64)
constexpr float LOG2E = 1.44269504088896f;
constexpr float SCALE_LOG2E = SCALE * LOG2E;

__device__ __forceinline__ float fast_exp2(float x) {
#if __has_builtin(__builtin_amdgcn_exp2f)
  return __builtin_amdgcn_exp2f(x);
#else
  float r;
  asm("v_exp_f32 %0, %1\n\ts_nop 1" : "=v"(r) : "v"(x));
  return r;
#endif
}

__device__ __forceinline__ bf16x8 cvt8(f32x4 a, f32x4 b) {
  bf16x8 r;
  r[0] = (bf16)a[0]; r[1] = (bf16)a[1]; r[2] = (bf16)a[2]; r[3] = (bf16)a[3];
  r[4] = (bf16)b[0]; r[5] = (bf16)b[1]; r[6] = (bf16)b[2]; r[7] = (bf16)b[3];
  return r;
}

__device__ __forceinline__ unsigned pack2(float lo, float hi) {
  union { bf16 h[2]; unsigned u; } r;
  r.h[0] = (bf16)lo; r.h[1] = (bf16)hi;
  return r.u;
}

// Exchange across the wave's 32-lane halves (verified R7).
__device__ __forceinline__ void swap32(unsigned &a, unsigned &b) {
#if __has_builtin(__builtin_amdgcn_permlane32_swap)
  i32x2 r = __builtin_amdgcn_permlane32_swap((int)a, (int)b, false, false);
  a = (unsigned)r[0]; b = (unsigned)r[1];
#else
  int hi = (int)((threadIdx.x >> 5) & 1);
  unsigned xa = (unsigned)__shfl_xor((int)a, 32);
  unsigned xb = (unsigned)__shfl_xor((int)b, 32);
  unsigned na = hi ? xb : a;
  unsigned nb = hi ? b  : xa;
  a = na; b = nb;
#endif
}

// async global -> LDS, 16B per lane (dest = uniform base + lane*16)
__device__ __forceinline__ void gload_lds16(const bf16* g, bf16* l) {
  __builtin_amdgcn_global_load_lds(
      (const __attribute__((address_space(1))) void*)g,
      (__attribute__((address_space(3))) void*)l, 16, 0, 0);
}

// explicit drain of outstanding global_load_lds / ds ops (race hardening)
__device__ __forceinline__ void drain_mem() {
  asm volatile("s_waitcnt vmcnt(0) lgkmcnt(0)" ::: "memory");
}

// ---------------------------------------------------------------------------
// Kernel 0: fp32 -> bf16 convert of X and Wq|Wk|Wv (into d_out scratch).
// ---------------------------------------------------------------------------
__global__ __launch_bounds__(256) void cvt_bf16(
    const float* __restrict__ X,  const float* __restrict__ Wq,
    const float* __restrict__ Wk, const float* __restrict__ Wv,
    bf16* __restrict__ Xb, bf16* __restrict__ Wb) {
  int i = (blockIdx.x * 256 + threadIdx.x) * 8;
  const float* src; bf16* dst; int off;
  if (i < NX)               { src = X;  dst = Xb;          off = i; }
  else if (i < NX + NW)     { src = Wq; dst = Wb;          off = i - NX; }
  else if (i < NX + 2 * NW) { src = Wk; dst = Wb + NW;     off = i - NX - NW; }
  else                      { src = Wv; dst = Wb + 2 * NW; off = i - NX - 2 * NW; }
  f32x4 a = *(const f32x4*)(src + off);
  f32x4 b = *(const f32x4*)(src + off + 4);
  *(bf16x8*)(dst + off) = cvt8(a, b);
}

// ---------------------------------------------------------------------------
// Kernel 1: Y = Xb @ Wb[z]^T + b, bf16 in, bf16 out (m97 structure).
//   z==0 -> Q [8192,1024] PRE-SCALED by SCALE*LOG2E;  z==1 -> K;
//   z==2 -> V transposed per-head.
// ---------------------------------------------------------------------------
__global__ __launch_bounds__(256, 2) void qkv_gemm(
    const bf16* __restrict__ Xb, const bf16* __restrict__ Wb,
    const float* __restrict__ bq, const float* __restrict__ bk,
    const float* __restrict__ bv,
    bf16* __restrict__ Qo, bf16* __restrict__ Ko, bf16* __restrict__ Vt) {
  const int z = blockIdx.z;
  const bf16*  W    = Wb + (size_t)z * NW;
  const float* bias = (z == 0) ? bq : (z == 1) ? bk : bv;
  const float  osc  = (z == 0) ? SCALE_LOG2E : 1.0f;  // Q pre-scale

  __shared__ bf16 As[128 * 64];
  __shared__ bf16 Bs[128 * 64];

  const int tid  = threadIdx.x;
  const int lane = tid & 63;
  const int w    = tid >> 6;
  const int wr   = w >> 1, wc = w & 1;
  const int m0   = blockIdx.x * 128;
  const int n0   = blockIdx.y * 128;
  const int c    = lane & 15, g = lane >> 4;

  const int lr  = lane >> 3;
  const int lcs = ((lane & 7) ^ lr) * 8;
  const bf16* aSrc = Xb + (size_t)(m0 + w * 32 + lr) * DD + lcs;
  const bf16* bSrc = W  + (size_t)(n0 + w * 32 + lr) * DD + lcs;
  bf16* aDst = &As[(w * 32) * 64];
  bf16* bDst = &Bs[(w * 32) * 64];

  f32x4 acc[4][4];
#pragma unroll
  for (int i = 0; i < 4; ++i)
#pragma unroll
    for (int j = 0; j < 4; ++j) acc[i][j] = f32x4{0.f, 0.f, 0.f, 0.f};

  for (int k0 = 0; k0 < DD; k0 += 64) {
    __syncthreads();   // previous compute done (WAR on LDS)
#pragma unroll
    for (int cc = 0; cc < 4; ++cc) {
      gload_lds16(aSrc + (size_t)cc * 8 * DD + k0, aDst + cc * 512);
      gload_lds16(bSrc + (size_t)cc * 8 * DD + k0, bDst + cc * 512);
    }
    drain_mem();
    __syncthreads();   // tile ready

#pragma unroll
    for (int kk = 0; kk < 64; kk += 32) {
      bf16x8 af[4], bfr[4];
#pragma unroll
      for (int m = 0; m < 4; ++m) {
        int row = wr * 64 + m * 16 + c;
        af[m] = *(const bf16x8*)(&As[row * 64 + (((kk >> 3) + g) ^ (row & 7)) * 8]);
      }
#pragma unroll
      for (int n = 0; n < 4; ++n) {
        int row = wc * 64 + n * 16 + c;
        bfr[n] = *(const bf16x8*)(&Bs[row * 64 + (((kk >> 3) + g) ^ (row & 7)) * 8]);
      }
#pragma unroll
      for (int m = 0; m < 4; ++m)
#pragma unroll
        for (int n = 0; n < 4; ++n)
          acc[m][n] = MFMA16(af[m], bfr[n], acc[m][n]);
    }
  }

#pragma unroll
  for (int n = 0; n < 4; ++n) {
    int colg = n0 + wc * 64 + n * 16 + c;
    float bv_ = bias[colg];
#pragma unroll
    for (int m = 0; m < 4; ++m) {
      int rowg = m0 + wr * 64 + m * 16 + g * 4;
      f32x4 a = acc[m][n];
      if (z < 2) {
        bf16* dst = (z == 0) ? Qo : Ko;
#pragma unroll
        for (int j = 0; j < 4; ++j)
          dst[(size_t)(rowg + j) * DD + colg] = (bf16)((a[j] + bv_) * osc);
      } else {
        int bi = rowg >> 11, s = rowg & 2047;
        int hh = colg >> 6, dd = colg & 63;
        bf16x4 pv;
#pragma unroll
        for (int j = 0; j < 4; ++j) pv[j] = (bf16)(a[j] + bv_);
        *(bf16x4*)(&Vt[(((size_t)bi * HH + hh) * HD + dd) * SS + s]) = pv;
      }
    }
  }
}

// ---------------------------------------------------------------------------
// Kernel 2: flash attention, 32x32x16 MFMA. Grid (B*H, S/128), 4 waves.
// LDS map: Ks[2] @0 (2x8KB), Vs[2] @16384, Ms @32768 (8KB, mask*LOG2E as
// QK^T C-operand; Q pre-scaled -> MFMA out = exp2 argument directly).
// lsum via per-lane lacc + one shfl_xor(32) (R10 verified path).
// Explicit vmcnt/lgkm drain before each tile barrier (race hardening).
// ---------------------------------------------------------------------------
__global__ __launch_bounds__(256) void attn(
    const bf16* __restrict__ Q,   // [B*S, D] (pre-scaled)
    const bf16* __restrict__ K,   // [B*S, D]
    const bf16* __restrict__ Vt,  // [(b*16+h)*64 + d][S]
    const float* __restrict__ mask,  // [B, S] additive
    float* __restrict__ out) {       // [B, S, D] fp32
  __shared__ __align__(16) char smem[40960];

  const int bh = blockIdx.x;  // 0..63
  const int qb = blockIdx.y;  // 0..15
  const int b = bh >> 4, h = bh & 15;
  const int tid = threadIdx.x;
  const int lane = tid & 63;
  const int w = tid >> 6;
  const int l31 = lane & 31, hi = lane >> 5;
  const int hi4 = hi * 4, hi8 = hi * 8;
  const int qg = qb * 128 + w * 32 + l31;  // this lane's q row

  const bf16* qptr = Q + ((size_t)(b * SS + qg)) * DD + h * HD;
  bf16x8 qB[4];
#pragma unroll
  for (int ks = 0; ks < 4; ++ks)
    qB[ks] = *(const bf16x8*)(qptr + ks * 16 + hi8);

  // 4 shared fragment offsets (bytes): row part + XOR-permuted chunk.
  int off[4];
#pragma unroll
  for (int x = 0; x < 4; ++x)
    off[x] = l31 * 128 + (((2 * x + hi) ^ (l31 & 7)) * 16);

  // staging geometry (global_load_lds): 8 rows x 8 slots per call.
  const int lr  = lane >> 3;
  const int lc  = ((lane & 7) ^ lr) * 8;   // pre-swizzled source chunk
  const int r0  = w * 16 + lr;
  const bf16* kpA = K  + ((size_t)b * SS + r0) * DD + h * HD + lc;
  const bf16* kpB = kpA + (size_t)8 * DD;
  const bf16* vpA = Vt + ((size_t)bh * HD + r0) * SS + lc;
  const bf16* vpB = vpA + (size_t)8 * SS;
  bf16* kD0 = (bf16*)(smem + w * 2048);
  bf16* vD0 = (bf16*)(smem + 16384 + w * 2048);

  f32x4 lacc = {0.f, 0.f, 0.f, 0.f};
  f32x16 acc[2] = {};

  // ---- prologue: mask*LOG2E -> Ms; stage tile 0 into buf 0 ----
  {
    const float* mbase = mask + b * SS;
    f32x4 m0 = *(const f32x4*)(mbase + tid * 8);
    f32x4 m1 = *(const f32x4*)(mbase + tid * 8 + 4);
    *(f32x4*)(smem + 32768 + tid * 32)      = m0 * LOG2E;
    *(f32x4*)(smem + 32768 + tid * 32 + 16) = m1 * LOG2E;
  }
  gload_lds16(kpA, kD0);
  gload_lds16(kpB, kD0 + 512);
  gload_lds16(vpA, vD0);
  gload_lds16(vpB, vD0 + 512);
  kpA += (size_t)64 * DD; kpB += (size_t)64 * DD;
  vpA += 64;              vpB += 64;
  drain_mem();
  __syncthreads();

  for (int t2 = 0; t2 < 16; ++t2) {
#pragma unroll
    for (int half = 0; half < 2; ++half) {
      const int t = t2 * 2 + half;
      const bool last = (t == 31);

      // ---- prefetch tile t+1 into buffer half^1 (async) ----
      if (!last) {
        bf16* kD = (bf16*)(smem + (half ^ 1) * 8192 + w * 2048);
        bf16* vD = (bf16*)(smem + 16384 + (half ^ 1) * 8192 + w * 2048);
        gload_lds16(kpA, kD);
        gload_lds16(kpB, kD + 512);
        gload_lds16(vpA, vD);
        gload_lds16(vpB, vD + 512);
        kpA += (size_t)64 * DD; kpB += (size_t)64 * DD;
        vpA += 64;              vpB += 64;
      }

      // ---- QK^T with mask*LOG2E as C-operand (Q pre-scaled) ----
      const char* mb = smem + (t * 256 + hi4 * 4);
      union { f32x16 v; f32x4 q[4]; } st[2];
#pragma unroll
      for (int kvb = 0; kvb < 2; ++kvb)
#pragma unroll
        for (int rg = 0; rg < 4; ++rg)
          st[kvb].q[rg] = *(const f32x4*)(mb + 32768 + kvb * 128 + rg * 32);

      __builtin_amdgcn_s_setprio(1);
#pragma unroll
      for (int kvb = 0; kvb < 2; ++kvb) {
#pragma unroll
        for (int ks = 0; ks < 4; ++ks) {
          bf16x8 ka = *(const bf16x8*)(smem + off[ks] + kvb * 4096 + half * 8192);
          st[kvb].v = MFMA32(ka, qB[ks], st[kvb].v);
        }
      }
      __builtin_amdgcn_s_setprio(0);

      // ---- V^T frags (issue early) ----
      bf16x8 va[2][4];
#pragma unroll
      for (int db = 0; db < 2; ++db)
#pragma unroll
        for (int sl = 0; sl < 4; ++sl)
          va[db][sl] = *(const bf16x8*)(smem + 16384 + off[sl] + db * 4096 + half * 8192);

      // ---- softmax: p = exp2(st) -- bare exp; lacc partial lsum ----
#pragma unroll
      for (int kvb = 0; kvb < 2; ++kvb)
#pragma unroll
        for (int r = 0; r < 16; ++r) {
          float e = fast_exp2(st[kvb].v[r]);
          st[kvb].v[r] = e;
          lacc[r & 3] += e;
        }

      // ---- P repack (pack + permlane32_swap) and PV MFMAs ----
      __builtin_amdgcn_s_setprio(1);
#pragma unroll
      for (int kvb = 0; kvb < 2; ++kvb) {
#pragma unroll
        for (int s2 = 0; s2 < 2; ++s2) {
          unsigned L0 = pack2(st[kvb].v[8 * s2 + 0], st[kvb].v[8 * s2 + 1]);
          unsigned L1 = pack2(st[kvb].v[8 * s2 + 2], st[kvb].v[8 * s2 + 3]);
          unsigned H0 = pack2(st[kvb].v[8 * s2 + 4], st[kvb].v[8 * s2 + 5]);
          unsigned H1 = pack2(st[kvb].v[8 * s2 + 6], st[kvb].v[8 * s2 + 7]);
          swap32(L0, H0);
          swap32(L1, H1);
          union { unsigned u[4]; bf16x8 v; } pb;
          pb.u[0] = L0; pb.u[1] = L1; pb.u[2] = H0; pb.u[3] = H1;
          const int sl = kvb * 2 + s2;
          acc[0] = MFMA32(va[0][sl], pb.v, acc[0]);
          acc[1] = MFMA32(va[1][sl], pb.v, acc[1]);
        }
      }
      __builtin_amdgcn_s_setprio(0);

      drain_mem();       // explicit: prefetched gload_lds writes landed
      __syncthreads();
    }
  }

  // ---- lsum: halves hold disjoint kv subsets; combine across hi ----
  float ls = lacc[0] + lacc[1] + lacc[2] + lacc[3];
  ls += __shfl_xor(ls, 32);
  const float inv = 1.0f / ls;

  // ---- store ctx[qg][d] = acc^T * inv;  d = 32db + 8rg + 4hi + j ----
  float* op = out + ((size_t)(b * SS + qg)) * DD + h * HD;
#pragma unroll
  for (int db = 0; db < 2; ++db)
#pragma unroll
    for (int rg = 0; rg < 4; ++rg) {
      f32x4 v;
#pragma unroll
      for (int j = 0; j < 4; ++j) v[j] = acc[db][rg * 4 + j] * inv;
      *(f32x4*)(op + db * 32 + rg * 8 + hi4) = v;
    }
}

// ---------------------------------------------------------------------------
extern "C" void kernel_launch(void* const* d_in, const int* in_sizes, int n_in,
                              void* d_out, int out_size, void* d_ws, size_t ws_size,
                              hipStream_t stream) {
  const float* X    = (const float*)d_in[0];
  const float* mask = (const float*)d_in[1];
  const float* Wq   = (const float*)d_in[2];
  const float* bq   = (const float*)d_in[3];
  const float* Wk   = (const float*)d_in[4];
  const float* bk   = (const float*)d_in[5];
  const float* Wv   = (const float*)d_in[6];
  const float* bv   = (const float*)d_in[7];

  // workspace: Q | K | Vt (bf16, 16 MiB each)
  bf16* Qw = (bf16*)d_ws;
  bf16* Kw = Qw + (size_t)NX;
  bf16* Vt = Kw + (size_t)NX;
  // bf16 scratch for converted inputs lives in d_out (attn overwrites later).
  bf16* Xb = (bf16*)d_out;            // 16 MiB
  bf16* Wb = Xb + (size_t)NX;         // 6 MiB (Wq|Wk|Wv)

  cvt_bf16<<<(NX + 3 * NW) / 2048, 256, 0, stream>>>(X, Wq, Wk, Wv, Xb, Wb);

  dim3 g1((BB * SS) / 128, DD / 128, 3);
  qkv_gemm<<<g1, 256, 0, stream>>>(Xb, Wb, bq, bk, bv, Qw, Kw, Vt);

  dim3 g2(BB * HH, SS / 128);  // 64 x 16
  attn<<<g2, 256, 0, stream>>>(Qw, Kw, Vt, mask, (float*)d_out);
}

// Round 13
// 161.453 us; speedup vs baseline: 3.6570x; 1.0082x over previous
//
#include <hip/hip_runtime.h>

// ---------------------------------------------------------------------------
// RoBERTa self-attention: QKV projection (bf16 MFMA) + flash attention.
// B=4, S=2048, D=1024, H=16, HD=64.  fp32 in/out, bf16 internal, fp32 acc.
// R13: retry lsum-via-ones-MFMA (accL) now that the explicit vmcnt/lgkm
//      drain is in place. R11 evidence: accL math was CORRECT (first
//      validation passed); the post-timing divergence was a replay race --
//      most plausibly the missing drain that R12 added. Single-change A/B
//      vs R12: delete 32 lacc adds + final shfl per tile-wave (VALU is the
//      top pipe at 54%), +4 ones-MFMAs (MFMA pipe at 27% has headroom).
// ---------------------------------------------------------------------------

typedef __bf16 bf16;
typedef bf16  bf16x8 __attribute__((ext_vector_type(8)));
typedef bf16  bf16x4 __attribute__((ext_vector_type(4)));
typedef float f32x4  __attribute__((ext_vector_type(4)));
typedef float f32x16 __attribute__((ext_vector_type(16)));
typedef int   i32x2  __attribute__((ext_vector_type(2)));

#define MFMA16(A, B, C) __builtin_amdgcn_mfma_f32_16x16x32_bf16((A), (B), (C), 0, 0, 0)
#define MFMA32(A, B, C) __builtin_amdgcn_mfma_f32_32x32x16_bf16((A), (B), (C), 0, 0, 0)

constexpr int BB = 4, SS = 2048, DD = 1024, HH = 16, HD = 64;
constexpr int NX = BB * SS * DD;   // 8388608
constexpr int NW = DD * DD;        // 1048576
constexpr float SCALE = 0.125f;    // 1/sqrt(64)
constexpr float LOG2E = 1.44269504088896f;
constexpr float SCALE_LOG2E = SCALE * LOG2E;

__device__ __forceinline__ float fast_exp2(float x) {
#if __has_builtin(__builtin_amdgcn_exp2f)
  return __builtin_amdgcn_exp2f(x);
#else
  float r;
  asm("v_exp_f32 %0, %1\n\ts_nop 1" : "=v"(r) : "v"(x));
  return r;
#endif
}

__device__ __forceinline__ bf16x8 cvt8(f32x4 a, f32x4 b) {
  bf16x8 r;
  r[0] = (bf16)a[0]; r[1] = (bf16)a[1]; r[2] = (bf16)a[2]; r[3] = (bf16)a[3];
  r[4] = (bf16)b[0]; r[5] = (bf16)b[1]; r[6] = (bf16)b[2]; r[7] = (bf16)b[3];
  return r;
}

__device__ __forceinline__ unsigned pack2(float lo, float hi) {
  union { bf16 h[2]; unsigned u; } r;
  r.h[0] = (bf16)lo; r.h[1] = (bf16)hi;
  return r.u;
}

// Exchange across the wave's 32-lane halves (verified R7).
__device__ __forceinline__ void swap32(unsigned &a, unsigned &b) {
#if __has_builtin(__builtin_amdgcn_permlane32_swap)
  i32x2 r = __builtin_amdgcn_permlane32_swap((int)a, (int)b, false, false);
  a = (unsigned)r[0]; b = (unsigned)r[1];
#else
  int hi = (int)((threadIdx.x >> 5) & 1);
  unsigned xa = (unsigned)__shfl_xor((int)a, 32);
  unsigned xb = (unsigned)__shfl_xor((int)b, 32);
  unsigned na = hi ? xb : a;
  unsigned nb = hi ? b  : xa;
  a = na; b = nb;
#endif
}

// async global -> LDS, 16B per lane (dest = uniform base + lane*16)
__device__ __forceinline__ void gload_lds16(const bf16* g, bf16* l) {
  __builtin_amdgcn_global_load_lds(
      (const __attribute__((address_space(1))) void*)g,
      (__attribute__((address_space(3))) void*)l, 16, 0, 0);
}

// explicit drain of outstanding global_load_lds / ds ops (race hardening;
// R12 added this and the post-timing divergence disappeared)
__device__ __forceinline__ void drain_mem() {
  asm volatile("s_waitcnt vmcnt(0) lgkmcnt(0)" ::: "memory");
}

// ---------------------------------------------------------------------------
// Kernel 0: fp32 -> bf16 convert of X and Wq|Wk|Wv (into d_out scratch).
// ---------------------------------------------------------------------------
__global__ __launch_bounds__(256) void cvt_bf16(
    const float* __restrict__ X,  const float* __restrict__ Wq,
    const float* __restrict__ Wk, const float* __restrict__ Wv,
    bf16* __restrict__ Xb, bf16* __restrict__ Wb) {
  int i = (blockIdx.x * 256 + threadIdx.x) * 8;
  const float* src; bf16* dst; int off;
  if (i < NX)               { src = X;  dst = Xb;          off = i; }
  else if (i < NX + NW)     { src = Wq; dst = Wb;          off = i - NX; }
  else if (i < NX + 2 * NW) { src = Wk; dst = Wb + NW;     off = i - NX - NW; }
  else                      { src = Wv; dst = Wb + 2 * NW; off = i - NX - 2 * NW; }
  f32x4 a = *(const f32x4*)(src + off);
  f32x4 b = *(const f32x4*)(src + off + 4);
  *(bf16x8*)(dst + off) = cvt8(a, b);
}

// ---------------------------------------------------------------------------
// Kernel 1: Y = Xb @ Wb[z]^T + b, bf16 in, bf16 out (m97 structure).
//   z==0 -> Q [8192,1024] PRE-SCALED by SCALE*LOG2E;  z==1 -> K;
//   z==2 -> V transposed per-head.
// ---------------------------------------------------------------------------
__global__ __launch_bounds__(256, 2) void qkv_gemm(
    const bf16* __restrict__ Xb, const bf16* __restrict__ Wb,
    const float* __restrict__ bq, const float* __restrict__ bk,
    const float* __restrict__ bv,
    bf16* __restrict__ Qo, bf16* __restrict__ Ko, bf16* __restrict__ Vt) {
  const int z = blockIdx.z;
  const bf16*  W    = Wb + (size_t)z * NW;
  const float* bias = (z == 0) ? bq : (z == 1) ? bk : bv;
  const float  osc  = (z == 0) ? SCALE_LOG2E : 1.0f;  // Q pre-scale

  __shared__ bf16 As[128 * 64];
  __shared__ bf16 Bs[128 * 64];

  const int tid  = threadIdx.x;
  const int lane = tid & 63;
  const int w    = tid >> 6;
  const int wr   = w >> 1, wc = w & 1;
  const int m0   = blockIdx.x * 128;
  const int n0   = blockIdx.y * 128;
  const int c    = lane & 15, g = lane >> 4;

  const int lr  = lane >> 3;
  const int lcs = ((lane & 7) ^ lr) * 8;
  const bf16* aSrc = Xb + (size_t)(m0 + w * 32 + lr) * DD + lcs;
  const bf16* bSrc = W  + (size_t)(n0 + w * 32 + lr) * DD + lcs;
  bf16* aDst = &As[(w * 32) * 64];
  bf16* bDst = &Bs[(w * 32) * 64];

  f32x4 acc[4][4];
#pragma unroll
  for (int i = 0; i < 4; ++i)
#pragma unroll
    for (int j = 0; j < 4; ++j) acc[i][j] = f32x4{0.f, 0.f, 0.f, 0.f};

  for (int k0 = 0; k0 < DD; k0 += 64) {
    __syncthreads();   // previous compute done (WAR on LDS)
#pragma unroll
    for (int cc = 0; cc < 4; ++cc) {
      gload_lds16(aSrc + (size_t)cc * 8 * DD + k0, aDst + cc * 512);
      gload_lds16(bSrc + (size_t)cc * 8 * DD + k0, bDst + cc * 512);
    }
    drain_mem();
    __syncthreads();   // tile ready

#pragma unroll
    for (int kk = 0; kk < 64; kk += 32) {
      bf16x8 af[4], bfr[4];
#pragma unroll
      for (int m = 0; m < 4; ++m) {
        int row = wr * 64 + m * 16 + c;
        af[m] = *(const bf16x8*)(&As[row * 64 + (((kk >> 3) + g) ^ (row & 7)) * 8]);
      }
#pragma unroll
      for (int n = 0; n < 4; ++n) {
        int row = wc * 64 + n * 16 + c;
        bfr[n] = *(const bf16x8*)(&Bs[row * 64 + (((kk >> 3) + g) ^ (row & 7)) * 8]);
      }
#pragma unroll
      for (int m = 0; m < 4; ++m)
#pragma unroll
        for (int n = 0; n < 4; ++n)
          acc[m][n] = MFMA16(af[m], bfr[n], acc[m][n]);
    }
  }

#pragma unroll
  for (int n = 0; n < 4; ++n) {
    int colg = n0 + wc * 64 + n * 16 + c;
    float bv_ = bias[colg];
#pragma unroll
    for (int m = 0; m < 4; ++m) {
      int rowg = m0 + wr * 64 + m * 16 + g * 4;
      f32x4 a = acc[m][n];
      if (z < 2) {
        bf16* dst = (z == 0) ? Qo : Ko;
#pragma unroll
        for (int j = 0; j < 4; ++j)
          dst[(size_t)(rowg + j) * DD + colg] = (bf16)((a[j] + bv_) * osc);
      } else {
        int bi = rowg >> 11, s = rowg & 2047;
        int hh = colg >> 6, dd = colg & 63;
        bf16x4 pv;
#pragma unroll
        for (int j = 0; j < 4; ++j) pv[j] = (bf16)(a[j] + bv_);
        *(bf16x4*)(&Vt[(((size_t)bi * HH + hh) * HD + dd) * SS + s]) = pv;
      }
    }
  }
}

// ---------------------------------------------------------------------------
// Kernel 2: flash attention, 32x32x16 MFMA. Grid (B*H, S/128), 4 waves.
// LDS map: Ks[2] @0 (2x8KB), Vs[2] @16384, Ms @32768 (8KB, mask*LOG2E as
// QK^T C-operand; Q pre-scaled -> MFMA out = exp2 argument directly).
// lsum via ones-MFMA into accL: every reg of accL = per-q-column sum of P
// (col = lane&31 for BOTH hi halves), so accL[0] is the lane's full lsum.
// Explicit vmcnt/lgkm drain before each tile barrier (race hardening).
// ---------------------------------------------------------------------------
__global__ __launch_bounds__(256) void attn(
    const bf16* __restrict__ Q,   // [B*S, D] (pre-scaled)
    const bf16* __restrict__ K,   // [B*S, D]
    const bf16* __restrict__ Vt,  // [(b*16+h)*64 + d][S]
    const float* __restrict__ mask,  // [B, S] additive
    float* __restrict__ out) {       // [B, S, D] fp32
  __shared__ __align__(16) char smem[40960];

  const int bh = blockIdx.x;  // 0..63
  const int qb = blockIdx.y;  // 0..15
  const int b = bh >> 4, h = bh & 15;
  const int tid = threadIdx.x;
  const int lane = tid & 63;
  const int w = tid >> 6;
  const int l31 = lane & 31, hi = lane >> 5;
  const int hi4 = hi * 4, hi8 = hi * 8;
  const int qg = qb * 128 + w * 32 + l31;  // this lane's q row

  const bf16* qptr = Q + ((size_t)(b * SS + qg)) * DD + h * HD;
  bf16x8 qB[4];
#pragma unroll
  for (int ks = 0; ks < 4; ++ks)
    qB[ks] = *(const bf16x8*)(qptr + ks * 16 + hi8);

  // ones A-frag for the lsum MFMA
  bf16x8 ones;
#pragma unroll
  for (int i = 0; i < 8; ++i) ones[i] = (bf16)1.0f;

  // 4 shared fragment offsets (bytes): row part + XOR-permuted chunk.
  int off[4];
#pragma unroll
  for (int x = 0; x < 4; ++x)
    off[x] = l31 * 128 + (((2 * x + hi) ^ (l31 & 7)) * 16);

  // staging geometry (global_load_lds): 8 rows x 8 slots per call.
  const int lr  = lane >> 3;
  const int lc  = ((lane & 7) ^ lr) * 8;   // pre-swizzled source chunk
  const int r0  = w * 16 + lr;
  const bf16* kpA = K  + ((size_t)b * SS + r0) * DD + h * HD + lc;
  const bf16* kpB = kpA + (size_t)8 * DD;
  const bf16* vpA = Vt + ((size_t)bh * HD + r0) * SS + lc;
  const bf16* vpB = vpA + (size_t)8 * SS;
  bf16* kD0 = (bf16*)(smem + w * 2048);
  bf16* vD0 = (bf16*)(smem + 16384 + w * 2048);

  f32x16 acc[2] = {};
  f32x16 accL = {};

  // ---- prologue: mask*LOG2E -> Ms; stage tile 0 into buf 0 ----
  {
    const float* mbase = mask + b * SS;
    f32x4 m0 = *(const f32x4*)(mbase + tid * 8);
    f32x4 m1 = *(const f32x4*)(mbase + tid * 8 + 4);
    *(f32x4*)(smem + 32768 + tid * 32)      = m0 * LOG2E;
    *(f32x4*)(smem + 32768 + tid * 32 + 16) = m1 * LOG2E;
  }
  gload_lds16(kpA, kD0);
  gload_lds16(kpB, kD0 + 512);
  gload_lds16(vpA, vD0);
  gload_lds16(vpB, vD0 + 512);
  kpA += (size_t)64 * DD; kpB += (size_t)64 * DD;
  vpA += 64;              vpB += 64;
  drain_mem();
  __syncthreads();

  for (int t2 = 0; t2 < 16; ++t2) {
#pragma unroll
    for (int half = 0; half < 2; ++half) {
      const int t = t2 * 2 + half;
      const bool last = (t == 31);

      // ---- prefetch tile t+1 into buffer half^1 (async) ----
      if (!last) {
        bf16* kD = (bf16*)(smem + (half ^ 1) * 8192 + w * 2048);
        bf16* vD = (bf16*)(smem + 16384 + (half ^ 1) * 8192 + w * 2048);
        gload_lds16(kpA, kD);
        gload_lds16(kpB, kD + 512);
        gload_lds16(vpA, vD);
        gload_lds16(vpB, vD + 512);
        kpA += (size_t)64 * DD; kpB += (size_t)64 * DD;
        vpA += 64;              vpB += 64;
      }

      // ---- QK^T with mask*LOG2E as C-operand (Q pre-scaled) ----
      const char* mb = smem + (t * 256 + hi4 * 4);
      union { f32x16 v; f32x4 q[4]; } st[2];
#pragma unroll
      for (int kvb = 0; kvb < 2; ++kvb)
#pragma unroll
        for (int rg = 0; rg < 4; ++rg)
          st[kvb].q[rg] = *(const f32x4*)(mb + 32768 + kvb * 128 + rg * 32);

      __builtin_amdgcn_s_setprio(1);
#pragma unroll
      for (int kvb = 0; kvb < 2; ++kvb) {
#pragma unroll
        for (int ks = 0; ks < 4; ++ks) {
          bf16x8 ka = *(const bf16x8*)(smem + off[ks] + kvb * 4096 + half * 8192);
          st[kvb].v = MFMA32(ka, qB[ks], st[kvb].v);
        }
      }
      __builtin_amdgcn_s_setprio(0);

      // ---- V^T frags (issue early) ----
      bf16x8 va[2][4];
#pragma unroll
      for (int db = 0; db < 2; ++db)
#pragma unroll
        for (int sl = 0; sl < 4; ++sl)
          va[db][sl] = *(const bf16x8*)(smem + 16384 + off[sl] + db * 4096 + half * 8192);

      // ---- softmax: p = exp2(st) -- bare exp, no mul/add ----
#pragma unroll
      for (int kvb = 0; kvb < 2; ++kvb)
#pragma unroll
        for (int r = 0; r < 16; ++r)
          st[kvb].v[r] = fast_exp2(st[kvb].v[r]);

      // ---- P repack (pack + permlane32_swap), PV + lsum MFMAs ----
      __builtin_amdgcn_s_setprio(1);
#pragma unroll
      for (int kvb = 0; kvb < 2; ++kvb) {
#pragma unroll
        for (int s2 = 0; s2 < 2; ++s2) {
          unsigned L0 = pack2(st[kvb].v[8 * s2 + 0], st[kvb].v[8 * s2 + 1]);
          unsigned L1 = pack2(st[kvb].v[8 * s2 + 2], st[kvb].v[8 * s2 + 3]);
          unsigned H0 = pack2(st[kvb].v[8 * s2 + 4], st[kvb].v[8 * s2 + 5]);
          unsigned H1 = pack2(st[kvb].v[8 * s2 + 6], st[kvb].v[8 * s2 + 7]);
          swap32(L0, H0);
          swap32(L1, H1);
          union { unsigned u[4]; bf16x8 v; } pb;
          pb.u[0] = L0; pb.u[1] = L1; pb.u[2] = H0; pb.u[3] = H1;
          const int sl = kvb * 2 + s2;
          acc[0] = MFMA32(va[0][sl], pb.v, acc[0]);
          acc[1] = MFMA32(va[1][sl], pb.v, acc[1]);
          accL   = MFMA32(ones,      pb.v, accL);
        }
      }
      __builtin_amdgcn_s_setprio(0);

      drain_mem();       // explicit: prefetched gload_lds writes landed
      __syncthreads();
    }
  }

  // ---- accL[0] = full lsum for this lane's q column (col=l31, both hi) ----
  const float inv = 1.0f / accL[0];

  // ---- store ctx[qg][d] = acc^T * inv;  d = 32db + 8rg + 4hi + j ----
  float* op = out + ((size_t)(b * SS + qg)) * DD + h * HD;
#pragma unroll
  for (int db = 0; db < 2; ++db)
#pragma unroll
    for (int rg = 0; rg < 4; ++rg) {
      f32x4 v;
#pragma unroll
      for (int j = 0; j < 4; ++j) v[j] = acc[db][rg * 4 + j] * inv;
      *(f32x4*)(op + db * 32 + rg * 8 + hi4) = v;
    }
}

// ---------------------------------------------------------------------------
extern "C" void kernel_launch(void* const* d_in, const int* in_sizes, int n_in,
                              void* d_out, int out_size, void* d_ws, size_t ws_size,
                              hipStream_t stream) {
  const float* X    = (const float*)d_in[0];
  const float* mask = (const float*)d_in[1];
  const float* Wq   = (const float*)d_in[2];
  const float* bq   = (const float*)d_in[3];
  const float* Wk   = (const float*)d_in[4];
  const float* bk   = (const float*)d_in[5];
  const float* Wv   = (const float*)d_in[6];
  const float* bv   = (const float*)d_in[7];

  // workspace: Q | K | Vt (bf16, 16 MiB each)
  bf16* Qw = (bf16*)d_ws;
  bf16* Kw = Qw + (size_t)NX;
  bf16* Vt = Kw + (size_t)NX;
  // bf16 scratch for converted inputs lives in d_out (attn overwrites later).
  bf16* Xb = (bf16*)d_out;            // 16 MiB
  bf16* Wb = Xb + (size_t)NX;         // 6 MiB (Wq|Wk|Wv)

  cvt_bf16<<<(NX + 3 * NW) / 2048, 256, 0, stream>>>(X, Wq, Wk, Wv, Xb, Wb);

  dim3 g1((BB * SS) / 128, DD / 128, 3);
  qkv_gemm<<<g1, 256, 0, stream>>>(Xb, Wb, bq, bk, bv, Qw, Kw, Vt);

  dim3 g2(BB * HH, SS / 128);  // 64 x 16
  attn<<<g2, 256, 0, stream>>>(Qw, Kw, Vt, mask, (float*)d_out);
}